// Round 11
// baseline (1049.044 us; speedup 1.0000x reference)
//
#include <hip/hip_runtime.h>
#include <math.h>

#define L_  4
#define B_  2
#define Q_  1024
#define M_  1024
#define D_  1024
#define H_  16
#define DH_ 64
#define DI_ 4096
#define KL_ (M_ + Q_)   // 2048

typedef __attribute__((ext_vector_type(8))) short short8v;  // 8 bf16 (4 VGPRs)
typedef __attribute__((ext_vector_type(4))) float f32x4;

__device__ __forceinline__ short f2bf(float f) {
    union { float f; unsigned u; } x; x.f = f;
    return (short)((x.u + 0x7FFFu + ((x.u >> 16) & 1)) >> 16);  // RNE
}
__device__ __forceinline__ unsigned pack2bf(float a, float b) {
    return (unsigned)(unsigned short)f2bf(a) | ((unsigned)(unsigned short)f2bf(b) << 16);
}
__device__ __forceinline__ float bf2f(unsigned short u) {
    union { unsigned u; float f; } x; x.u = (unsigned)u << 16; return x.f;
}
__device__ __forceinline__ unsigned cvtpk(float lo, float hi) {
    unsigned r;
    asm("v_cvt_pk_bf16_f32 %0, %1, %2" : "=v"(r) : "v"(lo), "v"(hi));
    return r;
}
__device__ __forceinline__ void gload_lds16(const short* g, short* l) {
    __builtin_amdgcn_global_load_lds((const __attribute__((address_space(1))) unsigned int*)(const void*)g,
                                     (__attribute__((address_space(3))) unsigned int*)(void*)l, 16, 0, 0);
}
// XOR swizzle key (in shorts) for stride-64-short LDS tiles
__device__ __forceinline__ int swz(int row) {
    return ((row & 7) ^ ((row >> 3) & 7)) << 3;
}
// k-permutation for the PV contraction (applied to BOTH P and V_T k index)
__device__ __forceinline__ int kperm(int k) {
    return 4 * (k & 15) + (k >> 4);
}

// ---------------- positional embedding p[KL][D] (bf16) ----------------
__global__ __launch_bounds__(256) void pos_emb_bf(short* __restrict__ p) {
    int idx = blockIdx.x * 256 + threadIdx.x;
    int k = idx >> 10;
    int i = idx & (D_ - 1);
    float pos = (float)(KL_ - 1 - k);
    int j = (i < D_ / 2) ? i : (i - D_ / 2);
    float invf = powf(10000.0f, -((float)(2 * j) / (float)D_));
    float ang = pos * invf;
    p[idx] = f2bf((i < D_ / 2) ? sinf(ang) : cosf(ang));
}

// ---------------- f32 -> bf16 (4 elems/thread) ----------------
__global__ __launch_bounds__(256) void bfconv_kernel(const float* __restrict__ in,
                                                     short* __restrict__ out) {
    int i = (blockIdx.x * 256 + threadIdx.x) * 4;
    float4 v = *(const float4*)(in + i);
    uint2 o; o.x = pack2bf(v.x, v.y); o.y = pack2bf(v.z, v.w);
    *(uint2*)(out + i) = o;
}

// ---------------- concat memory[l] and x into xmemb [B][KL][D] bf16 ----------------
__global__ __launch_bounds__(256) void concat_bf(short* __restrict__ xmemb,
                                                 const float* __restrict__ mem_l,
                                                 const float* __restrict__ xc) {
    int idx = blockIdx.x * 256 + threadIdx.x;
    int d = idx & (D_ - 1);
    int k = (idx >> 10) & (KL_ - 1);
    int b = idx >> 21;
    float v = (k < M_) ? mem_l[((size_t)(b * M_ + k)) * D_ + d]
                       : xc[((size_t)(b * Q_ + (k - M_))) * D_ + d];
    xmemb[idx] = f2bf(v);
}

// ---------------- tiled transpose + f32->bf16: in[K][N] -> out[N][K] ----------------
__global__ __launch_bounds__(256) void transp_bf(const float* __restrict__ in,
                                                 short* __restrict__ out,
                                                 int K, int N) {
    __shared__ float t[32][33];
    int r = threadIdx.x >> 3, c4 = (threadIdx.x & 7) * 4;
    float4 v = *(const float4*)(in + (size_t)(blockIdx.y * 32 + r) * N + blockIdx.x * 32 + c4);
    t[r][c4 + 0] = v.x; t[r][c4 + 1] = v.y; t[r][c4 + 2] = v.z; t[r][c4 + 3] = v.w;
    __syncthreads();
    uint2 o;
    o.x = pack2bf(t[c4 + 0][r], t[c4 + 1][r]);
    o.y = pack2bf(t[c4 + 2][r], t[c4 + 3][r]);
    *(uint2*)(out + (size_t)(blockIdx.x * 32 + r) * K + blockIdx.y * 32 + c4) = o;
}

// ---------------- bf16 MFMA GEMM: C[M,N] = A[M,K] @ BT[N,K]^T ----------------
// 128xTN tile, BK=32, 4 waves. KS=2: blockIdx.z halves K, writes partial Cf planes.
template <int BIAS, int RELU, int OMODE, int TN, int KS = 1>
__global__ __launch_bounds__(256, 2) void gemm_bf(const short* __restrict__ A,
                                                  const short* __restrict__ BT,
                                                  const float* __restrict__ bias,
                                                  float* __restrict__ Cf,
                                                  short* __restrict__ C0,
                                                  short* __restrict__ C1,
                                                  short* __restrict__ C2,
                                                  int M, int N, int K) {
    __shared__ short A_s[128 * 32];
    __shared__ short B_s[TN * 32];
    const int tid = threadIdx.x;
    const int lane = tid & 63, w = tid >> 6;
    const int l15 = lane & 15, l4 = lane >> 4;
    constexpr int MF = (TN == 128) ? 4 : 2;
    const int wr = (TN == 128) ? (w >> 1) : w;
    const int wc = (TN == 128) ? (w & 1) : 0;
    const int arow0 = 32 * ((TN == 128) ? 2 * wr : w);
    const int brow0 = (TN == 128) ? 64 * wc : 0;
    const int row0 = blockIdx.y * 128, col0 = blockIdx.x * TN;
    const int kz = (KS == 2) ? blockIdx.z : 0;
    const int Kh = (KS == 2) ? (K >> 1) : K;
    const int kb = kz * Kh;

    const int lrow = lane >> 2;
    const int lk = (lane & 3) * 8;
    const short* Ag = A + (size_t)(row0 + 32 * w) * K;
    const short* Bg = BT + (size_t)(col0 + ((TN == 128) ? 32 : 16) * w) * K;

    f32x4 acc[MF][4] = {};

    for (int k0 = kb; k0 < kb + Kh; k0 += 32) {
        __syncthreads();
        gload_lds16(Ag + (size_t)lrow * K + k0 + lk,        &A_s[(32 * w) * 32]);
        gload_lds16(Ag + (size_t)(16 + lrow) * K + k0 + lk, &A_s[(32 * w + 16) * 32]);
        if (TN == 128) {
            gload_lds16(Bg + (size_t)lrow * K + k0 + lk,        &B_s[(32 * w) * 32]);
            gload_lds16(Bg + (size_t)(16 + lrow) * K + k0 + lk, &B_s[(32 * w + 16) * 32]);
        } else {
            gload_lds16(Bg + (size_t)lrow * K + k0 + lk,        &B_s[(16 * w) * 32]);
        }
        __syncthreads();
        short8v a[MF], bfr[4];
#pragma unroll
        for (int m = 0; m < MF; m++) a[m] = *(const short8v*)&A_s[(arow0 + 16 * m + l15) * 32 + 8 * l4];
#pragma unroll
        for (int n = 0; n < 4; n++) bfr[n] = *(const short8v*)&B_s[(brow0 + 16 * n + l15) * 32 + 8 * l4];
#pragma unroll
        for (int m = 0; m < MF; m++)
#pragma unroll
            for (int n = 0; n < 4; n++)
                acc[m][n] = __builtin_amdgcn_mfma_f32_16x16x32_bf16(a[m], bfr[n], acc[m][n], 0, 0, 0);
    }

    float* Cfz = Cf + (size_t)kz * M * N;
#pragma unroll
    for (int n = 0; n < 4; n++) {
        int col = col0 + brow0 + 16 * n + l15;
        float bv = (BIAS && (KS == 1 || kz == 0)) ? bias[col] : 0.0f;
#pragma unroll
        for (int m = 0; m < MF; m++) {
#pragma unroll
            for (int r = 0; r < 4; r++) {
                int row = row0 + arow0 + 16 * m + 4 * l4 + r;
                float v = acc[m][n][r] + bv;
                if (RELU) v = fmaxf(v, 0.0f);
                if (OMODE == 0) {
                    Cfz[(size_t)row * N + col] = v;
                } else if (OMODE == 1) {
                    C0[(size_t)row * N + col] = f2bf(v);
                } else {
                    int part = col >> 10, cc = col & 1023;
                    short* dst = part == 0 ? C0 : (part == 1 ? C1 : C2);
                    dst[(size_t)row * 1024 + cc] = f2bf(v);
                }
            }
        }
    }
}

// ---------------- MFMA fused attention v6 + kperm P/V path ----------------
// 512 blocks = (b, h, 64 q-rows). XCD pin: xcd=wg&7 serves h={2xcd,2xcd+1} x b.
// Double-buffered K/V tiles + 256-row R ring. AC/BD MFMA for tile t+1 issued BEFORE
// softmax(t). Defer-max (THR=8), lane-partial l, mask only on final tile.
// PV k-dim stored permuted (kperm) in BOTH P and V_T: P writes become 1 b64/row.
__global__ __launch_bounds__(256, 2) void attn_mfma(const short* __restrict__ qbf,
                                                    const short* __restrict__ kbf,
                                                    const short* __restrict__ vbf,
                                                    const short* __restrict__ rbh,
                                                    const float* __restrict__ rwb,
                                                    const float* __restrict__ rrb,
                                                    short* __restrict__ attnob) {
    __shared__ short K_s[2][64 * 64];
    __shared__ short V_T[2][64 * 64];   // V_T[d][kperm(k)], swizzled
    __shared__ short R_s[256 * 64];     // ring: phys = logical & 255
    __shared__ short P_s[4][16 * 64];   // per-wave P, k-permuted, swizzled

    const int tid = threadIdx.x;
    const int lane = tid & 63, w = tid >> 6;
    const int l15 = lane & 15, l4 = lane >> 4;
    const int lr8 = lane >> 3, oct = lane & 7;
    const int d0 = (tid & 7) * 8;

    // ---- XCD-pinned decode (512 blocks: xcd(8) x qp(16) x bl(4)) ----
    const int wg = blockIdx.x;
    const int xcd = wg & 7;
    const int qp = (wg >> 3) & 15;
    const int bl = (wg >> 7) & 3;
    const int h = xcd * 2 + (bl & 1);
    const int b = bl >> 1;
    const int qi = (qp & 1) ? (15 - (qp >> 1)) : (qp >> 1);   // work-pairing
    const int q0 = qi * 64;
    const int nt = qi + 17;
    const int jbase0 = (Q_ - 64) - q0;   // logical R row 0 -> global j

    // ---- Q frags: direct per-lane load + bias fuse (qbf is compact [B*Q][1024]) ----
    size_t qrow = ((size_t)(b * Q_ + q0 + 16 * w + l15)) * 1024 + h * 64;
    union U8 { uint4 u; unsigned short us[8]; };
    U8 qa, qb2;
    qa.u  = *(const uint4*)(qbf + qrow + 8 * l4);
    qb2.u = *(const uint4*)(qbf + qrow + 32 + 8 * l4);
    short8v qwf0, qwf1, qrf0, qrf1;
#pragma unroll
    for (int i = 0; i < 8; i++) {
        float qv0 = bf2f(qa.us[i]), qv1 = bf2f(qb2.us[i]);
        int c0 = h * 64 + 8 * l4 + i, c1 = c0 + 32;
        qwf0[i] = f2bf(qv0 + rwb[c0]); qwf1[i] = f2bf(qv1 + rwb[c1]);
        qrf0[i] = f2bf(qv0 + rrb[c0]); qrf1[i] = f2bf(qv1 + rrb[c1]);
    }

    // ---- prologue: K(0),K(1) -> K_s, R logical [0,256) -> ring, V(0) -> V_T[0] ----
#pragma unroll
    for (int c = 0; c < 2; c++) {
        int R0 = 16 * w + 8 * c;
        int row = R0 + lr8;
        gload_lds16(kbf + ((size_t)(b * KL_) + row) * 1024 + h * 64 + ((oct * 8) ^ swz(row)),
                    &K_s[0][R0 * 64]);
        gload_lds16(kbf + ((size_t)(b * KL_) + 64 + row) * 1024 + h * 64 + ((oct * 8) ^ swz(row)),
                    &K_s[1][R0 * 64]);
    }
#pragma unroll
    for (int c = 0; c < 8; c++) {
        int R0 = 64 * w + 8 * c;
        int row = R0 + lr8;
        int jl = jbase0 + row;   // < KL
        gload_lds16(rbh + (size_t)jl * 1024 + h * 64 + ((oct * 8) ^ swz(row)),
                    &R_s[R0 * 64]);
    }
    {
        U8 cv0[2];
#pragma unroll
        for (int it = 0; it < 2; it++) {
            int rr = (tid + it * 256) >> 3;
            cv0[it].u = *(const uint4*)(vbf + ((size_t)(b * KL_) + rr) * 1024 + h * 64 + d0);
        }
#pragma unroll
        for (int it = 0; it < 2; it++) {
            int rr = (tid + it * 256) >> 3;
            int kp = kperm(rr);
#pragma unroll
            for (int i = 0; i < 8; i++)
                V_T[0][(d0 + i) * 64 + (kp ^ swz(d0 + i))] = (short)cv0[it].us[i];
        }
    }
    asm volatile("s_waitcnt vmcnt(0) lgkmcnt(0)" ::: "memory");
    __builtin_amdgcn_sched_barrier(0);
    __builtin_amdgcn_s_barrier();
    __builtin_amdgcn_sched_barrier(0);

    f32x4 o[4];
    float m_r[4], l_p[4];
#pragma unroll
    for (int j = 0; j < 4; j++) o[j] = (f32x4){0.f, 0.f, 0.f, 0.f};
#pragma unroll
    for (int r = 0; r < 4; r++) { m_r[r] = -1e30f; l_p[r] = 0.0f; }

    int sl[4];
#pragma unroll
    for (int r = 0; r < 4; r++)
        sl[r] = (lane & 48) | ((l15 + 15 - (4 * l4 + r)) & 15);

    short* P_w = &P_s[w][0];
    const int rbase = 16 * (3 - w);

    // ---- pre-compute ac/zf for tile 0 ----
    f32x4 acA[4], zfA[5], acB[4], zfB[5];
#pragma unroll
    for (int j = 0; j < 4; j++) {
        int kk = 16 * j + l15, sz = swz(kk);
        short8v b0 = *(const short8v*)&K_s[0][kk * 64 + ((8 * l4) ^ sz)];
        short8v b1 = *(const short8v*)&K_s[0][kk * 64 + ((32 + 8 * l4) ^ sz)];
        f32x4 z = {0.f, 0.f, 0.f, 0.f};
        z = __builtin_amdgcn_mfma_f32_16x16x32_bf16(qwf0, b0, z, 0, 0, 0);
        z = __builtin_amdgcn_mfma_f32_16x16x32_bf16(qwf1, b1, z, 0, 0, 0);
        acA[j] = z;
    }
#pragma unroll
    for (int jb = 0; jb < 5; jb++) {
        int rp = (rbase + 16 * jb + l15) & 255;
        int sz = swz(rp);
        short8v b0 = *(const short8v*)&R_s[rp * 64 + ((8 * l4) ^ sz)];
        short8v b1 = *(const short8v*)&R_s[rp * 64 + ((32 + 8 * l4) ^ sz)];
        f32x4 z = {0.f, 0.f, 0.f, 0.f};
        z = __builtin_amdgcn_mfma_f32_16x16x32_bf16(qrf0, b0, z, 0, 0, 0);
        z = __builtin_amdgcn_mfma_f32_16x16x32_bf16(qrf1, b1, z, 0, 0, 0);
        zfA[jb] = z;
    }

    auto body = [&](f32x4 (&ac)[4], f32x4 (&zf)[5], f32x4 (&acn)[4], f32x4 (&zfn)[5], int t)
        __attribute__((always_inline)) {
        const int cb = t & 1, nb = (t + 1) & 1;
        // ---- (a) issue next loads ----
        uint4 pv2[2];
        if (t + 1 < nt) {
#pragma unroll
            for (int it = 0; it < 2; it++) {
                int rr = (tid + it * 256) >> 3;
                pv2[it] = *(const uint4*)(vbf + ((size_t)(b * KL_) + 64 * (t + 1) + rr) * 1024 + h * 64 + d0);
            }
        }
        if (t + 2 < nt) {
#pragma unroll
            for (int c = 0; c < 2; c++) {
                int R0 = 16 * w + 8 * c;
                int row = R0 + lr8;
                gload_lds16(kbf + ((size_t)(b * KL_) + 64 * (t + 2) + row) * 1024 + h * 64 + ((oct * 8) ^ swz(row)),
                            &K_s[cb][R0 * 64]);
            }
            // R ring chunk: logical [64t+256, 64t+320)
#pragma unroll
            for (int c = 0; c < 2; c++) {
                int R0 = 16 * w + 8 * c;
                int l0 = 64 * t + 256 + R0 + lr8;
                int ph = l0 & 255;
                int jl = jbase0 + l0;
                if (jl > KL_ - 1) jl = KL_ - 1;
                gload_lds16(rbh + (size_t)jl * 1024 + h * 64 + ((oct * 8) ^ swz(ph)),
                            &R_s[((64 * t + 256 + R0) & 255) * 64]);
            }
        }
        __builtin_amdgcn_sched_barrier(0);   // keep load issues ahead

        // ---- (b) MFMA for tile t+1 (overlaps softmax(t) below) ----
        if (t + 1 < nt) {
            __builtin_amdgcn_s_setprio(1);
#pragma unroll
            for (int j = 0; j < 4; j++) {
                int kk = 16 * j + l15, sz = swz(kk);
                short8v b0 = *(const short8v*)&K_s[nb][kk * 64 + ((8 * l4) ^ sz)];
                short8v b1 = *(const short8v*)&K_s[nb][kk * 64 + ((32 + 8 * l4) ^ sz)];
                f32x4 z = {0.f, 0.f, 0.f, 0.f};
                z = __builtin_amdgcn_mfma_f32_16x16x32_bf16(qwf0, b0, z, 0, 0, 0);
                z = __builtin_amdgcn_mfma_f32_16x16x32_bf16(qwf1, b1, z, 0, 0, 0);
                acn[j] = z;
            }
#pragma unroll
            for (int jb = 0; jb < 5; jb++) {
                int rp = (64 * (t + 1) + rbase + 16 * jb + l15) & 255;
                int sz = swz(rp);
                short8v b0 = *(const short8v*)&R_s[rp * 64 + ((8 * l4) ^ sz)];
                short8v b1 = *(const short8v*)&R_s[rp * 64 + ((32 + 8 * l4) ^ sz)];
                f32x4 z = {0.f, 0.f, 0.f, 0.f};
                z = __builtin_amdgcn_mfma_f32_16x16x32_bf16(qrf0, b0, z, 0, 0, 0);
                z = __builtin_amdgcn_mfma_f32_16x16x32_bf16(qrf1, b1, z, 0, 0, 0);
                zfn[jb] = z;
            }
            __builtin_amdgcn_s_setprio(0);
        }

        // ---- (c) softmax(t): dedup BD shuffles, defer-max, lane-partial l ----
        float sv[4][4], lmax[4];
#pragma unroll
        for (int r = 0; r < 4; r++) {
            int row = 4 * l4 + r;
            float bq[5];
#pragma unroll
            for (int s = 0; s < 5; s++) bq[s] = __shfl(zf[s][r], sl[r]);
#pragma unroll
            for (int j = 0; j < 4; j++) {
                float bd = (l15 > row) ? bq[j + 1] : bq[j];
                sv[j][r] = (ac[j][r] + bd) * 0.125f;
            }
        }
        if (t == nt - 1) {   // only the final tile has masked elements
#pragma unroll
            for (int j = 0; j < 4; j++)
#pragma unroll
                for (int r = 0; r < 4; r++)
                    if (64 * t + 16 * j + l15 > q0 + 16 * w + 4 * l4 + r + M_) sv[j][r] = -1e30f;
        }
#pragma unroll
        for (int r = 0; r < 4; r++) lmax[r] = fmaxf(fmaxf(sv[0][r], sv[1][r]), fmaxf(sv[2][r], sv[3][r]));
        bool ok = true;
#pragma unroll
        for (int r = 0; r < 4; r++) ok = ok && (lmax[r] <= m_r[r] + 8.0f);
        if (!__all(ok)) {
#pragma unroll
            for (int r = 0; r < 4; r++) {
                float v = lmax[r];
                v = fmaxf(v, __shfl_xor(v, 1));
                v = fmaxf(v, __shfl_xor(v, 2));
                v = fmaxf(v, __shfl_xor(v, 4));
                v = fmaxf(v, __shfl_xor(v, 8));
                float mnew = fmaxf(m_r[r], v);
                float c = __expf(m_r[r] - mnew);
                m_r[r] = mnew;
                l_p[r] *= c;
#pragma unroll
                for (int jd = 0; jd < 4; jd++) o[jd][r] *= c;
            }
        }
#pragma unroll
        for (int j = 0; j < 4; j++)
#pragma unroll
            for (int r = 0; r < 4; r++) {
                float pp = __expf(sv[j][r] - m_r[r]);
                sv[j][r] = pp;
                l_p[r] += pp;
            }

        // ---- (d) P -> per-wave swizzled LDS (k-permuted, 1 b64/row) -> A-frags; PV ----
#pragma unroll
        for (int r = 0; r < 4; r++) {
            int row = 4 * l4 + r;
            // k' = 4*l15 + j : shorts {j=0,1,2,3} contiguous
            uint2 pv;
            pv.x = cvtpk(sv[0][r], sv[1][r]);
            pv.y = cvtpk(sv[2][r], sv[3][r]);
            *(uint2*)&P_w[row * 64 + ((4 * l15) ^ swz(row))] = pv;
        }
        int szp = swz(l15);
        short8v pa0 = *(const short8v*)&P_w[l15 * 64 + ((8 * l4) ^ szp)];
        short8v pa1 = *(const short8v*)&P_w[l15 * 64 + ((32 + 8 * l4) ^ szp)];
        __builtin_amdgcn_s_setprio(1);
#pragma unroll
        for (int jd = 0; jd < 4; jd++) {
            int dd = 16 * jd + l15, sz = swz(dd);
            short8v v0 = *(const short8v*)&V_T[cb][dd * 64 + ((8 * l4) ^ sz)];
            short8v v1 = *(const short8v*)&V_T[cb][dd * 64 + ((32 + 8 * l4) ^ sz)];
            o[jd] = __builtin_amdgcn_mfma_f32_16x16x32_bf16(pa0, v0, o[jd], 0, 0, 0);
            o[jd] = __builtin_amdgcn_mfma_f32_16x16x32_bf16(pa1, v1, o[jd], 0, 0, 0);
        }
        __builtin_amdgcn_s_setprio(0);

        // ---- (e) write V(t+1) into V_T[nb] (k-permuted) ----
        if (t + 1 < nt) {
#pragma unroll
            for (int it = 0; it < 2; it++) {
                int rr = (tid + it * 256) >> 3;
                int kp = kperm(rr);
                U8 cv; cv.u = pv2[it];
#pragma unroll
                for (int i = 0; i < 8; i++)
                    V_T[nb][(d0 + i) * 64 + (kp ^ swz(d0 + i))] = (short)cv.us[i];
            }
            // ---- (f) single per-tile drain + barrier ----
            asm volatile("s_waitcnt vmcnt(0) lgkmcnt(0)" ::: "memory");
            __builtin_amdgcn_sched_barrier(0);
            __builtin_amdgcn_s_barrier();
            __builtin_amdgcn_sched_barrier(0);
        }
    };

    int t = 0;
    while (t < nt) {
        body(acA, zfA, acB, zfB, t); t++;
        if (t >= nt) break;
        body(acB, zfB, acA, zfA, t); t++;
    }

    // ---- final l reduce + normalize + store ----
    float l_r[4];
#pragma unroll
    for (int r = 0; r < 4; r++) {
        float v = l_p[r];
        v += __shfl_xor(v, 1);
        v += __shfl_xor(v, 2);
        v += __shfl_xor(v, 4);
        v += __shfl_xor(v, 8);
        l_r[r] = v;
    }
#pragma unroll
    for (int jd = 0; jd < 4; jd++) {
#pragma unroll
        for (int r = 0; r < 4; r++) {
            int qg = q0 + 16 * w + 4 * l4 + r;
            int dv = 16 * jd + l15;
            attnob[((size_t)(b * Q_ + qg)) * (H_ * DH_) + h * 64 + dv] = f2bf(o[jd][r] / l_r[r]);
        }
    }
}

// ---------------- layernorm: x = LN(x + a1 + a2) * g + b ; dual f32+bf16 out ----------------
__global__ __launch_bounds__(256) void ln_kernel(float* __restrict__ x,
                                                 short* __restrict__ xb,
                                                 const float* __restrict__ a1,
                                                 const float* __restrict__ a2,
                                                 const float* __restrict__ g,
                                                 const float* __restrict__ bb) {
    __shared__ float red[8];
    int row = blockIdx.x;
    int tid = threadIdx.x;
    float4 xv = ((const float4*)(x + (size_t)row * D_))[tid];
    float4 v1 = ((const float4*)(a1 + (size_t)row * D_))[tid];
    float4 v2 = ((const float4*)(a2 + (size_t)row * D_))[tid];
    float4 v;
    v.x = xv.x + v1.x + v2.x; v.y = xv.y + v1.y + v2.y;
    v.z = xv.z + v1.z + v2.z; v.w = xv.w + v1.w + v2.w;
    float s = v.x + v.y + v.z + v.w;
#pragma unroll
    for (int off = 32; off; off >>= 1) s += __shfl_xor(s, off);
    if ((tid & 63) == 0) red[tid >> 6] = s;
    __syncthreads();
    float mu = (red[0] + red[1] + red[2] + red[3]) * (1.0f / D_);
    float e0 = v.x - mu, e1 = v.y - mu, e2 = v.z - mu, e3 = v.w - mu;
    float sq = e0 * e0 + e1 * e1 + e2 * e2 + e3 * e3;
#pragma unroll
    for (int off = 32; off; off >>= 1) sq += __shfl_xor(sq, off);
    if ((tid & 63) == 0) red[4 + (tid >> 6)] = sq;
    __syncthreads();
    float var = (red[4] + red[5] + red[6] + red[7]) * (1.0f / D_);
    float rs = rsqrtf(var + 1e-5f);
    float4 gv = ((const float4*)g)[tid];
    float4 bv = ((const float4*)bb)[tid];
    float4 ov;
    ov.x = e0 * rs * gv.x + bv.x; ov.y = e1 * rs * gv.y + bv.y;
    ov.z = e2 * rs * gv.z + bv.z; ov.w = e3 * rs * gv.w + bv.w;
    ((float4*)(x + (size_t)row * D_))[tid] = ov;
    uint2 ob;
    ob.x = pack2bf(ov.x, ov.y);
    ob.y = pack2bf(ov.z, ov.w);
    *(uint2*)(xb + (size_t)row * D_ + tid * 4) = ob;
}

extern "C" void kernel_launch(void* const* d_in, const int* in_sizes, int n_in,
                              void* d_out, int out_size, void* d_ws, size_t ws_size,
                              hipStream_t stream) {
    const float* x    = (const float*)d_in[0];
    const float* mem  = (const float*)d_in[1];
    const float* Wqkv = (const float*)d_in[2];
    const float* Wr   = (const float*)d_in[3];
    const float* Wo   = (const float*)d_in[4];
    const float* rwb  = (const float*)d_in[5];
    const float* rrb  = (const float*)d_in[6];
    const float* ln1g = (const float*)d_in[7];
    const float* ln1b = (const float*)d_in[8];
    const float* ln2g = (const float*)d_in[9];
    const float* ln2b = (const float*)d_in[10];
    const float* Wff1 = (const float*)d_in[11];
    const float* bff1 = (const float*)d_in[12];
    const float* Wff2 = (const float*)d_in[13];
    const float* bff2 = (const float*)d_in[14];

    float* xc = (float*)d_out;

    // workspace layout (shorts unless noted)
    short* WqkvT = (short*)d_ws;              // [3072][1024]
    short* WoT   = WqkvT + 3145728;           // [1024][1024]
    short* Wff1T = WoT + 1048576;             // [4096][1024]
    short* Wff2T = Wff1T + 4194304;           // [1024][4096]
    short* WrT   = Wff2T + 4194304;           // [1024][1024]
    short* rbh   = WrT + 1048576;             // [2048][1024]
    short* xmemb = rbh + 2097152;             // [B*KL][1024]
    short* qbf   = xmemb + 4194304;           // [B*Q][1024] (compact now)
    short* kbf   = qbf + 4194304;             // [B*KL][1024]
    short* vbf   = kbf + 4194304;             // [B*KL][1024]
    short* attnob= vbf + 4194304;             // [B*Q][1024]
    short* xcb   = attnob + 2097152;          // [B*Q][1024]
    short* ff1ob = xcb + 2097152;             // [B*Q][4096]
    float* addbuf= (float*)(ff1ob + 8388608); // [2][B*Q][1024] f32 (split-K partials)
    short* pbf   = ff1ob;                     // alias: p bf16 [2048][1024], pre-loop only

    // r = p @ W_r  (bf16 MFMA)
    transp_bf<<<dim3(32, 32), 256, 0, stream>>>(Wr, WrT, 1024, 1024);
    pos_emb_bf<<<(KL_ * D_) / 256, 256, 0, stream>>>(pbf);
    gemm_bf<0, 0, 1, 64><<<dim3(16, 16), 256, 0, stream>>>(
        pbf, WrT, nullptr, nullptr, rbh, nullptr, nullptr, KL_, 1024, 1024);

    hipMemcpyAsync(xc, x, (size_t)B_ * Q_ * D_ * sizeof(float),
                   hipMemcpyDeviceToDevice, stream);
    bfconv_kernel<<<(B_ * Q_ * D_) / 1024, 256, 0, stream>>>(xc, xcb);

    for (int l = 0; l < L_; l++) {
        const float* mem_l = mem + (size_t)l * B_ * M_ * D_;

        transp_bf<<<dim3(96, 32), 256, 0, stream>>>(Wqkv + (size_t)l * 3145728, WqkvT, 1024, 3072);
        transp_bf<<<dim3(32, 32), 256, 0, stream>>>(Wo + (size_t)l * 1048576, WoT, 1024, 1024);
        transp_bf<<<dim3(128, 32), 256, 0, stream>>>(Wff1 + (size_t)l * 4194304, Wff1T, 1024, 4096);
        transp_bf<<<dim3(32, 128), 256, 0, stream>>>(Wff2 + (size_t)l * 4194304, Wff2T, 4096, 1024);

        concat_bf<<<(B_ * KL_ * D_) / 256, 256, 0, stream>>>(xmemb, mem_l, xc);

        // K,V over full KL rows (weight rows 1024..3071)
        gemm_bf<0, 0, 2, 128><<<dim3(16, 32), 256, 0, stream>>>(
            xmemb, WqkvT + (size_t)1024 * 1024, nullptr, nullptr, kbf, vbf, nullptr,
            B_ * KL_, 2048, 1024);
        // Q over x rows only (A = xcb, compact)
        gemm_bf<0, 0, 1, 128><<<dim3(8, 16), 256, 0, stream>>>(
            xcb, WqkvT, nullptr, nullptr, qbf, nullptr, nullptr, B_ * Q_, 1024, 1024);

        attn_mfma<<<B_ * H_ * (Q_ / 64), 256, 0, stream>>>(
            qbf, kbf, vbf, rbh, rwb, rrb, attnob);

        gemm_bf<0, 0, 0, 64, 2><<<dim3(16, 16, 2), 256, 0, stream>>>(
            attnob, WoT, nullptr, addbuf, nullptr, nullptr, nullptr, B_ * Q_, 1024, 1024);

        ln_kernel<<<B_ * Q_, 256, 0, stream>>>(xc, xcb, addbuf, addbuf + 2097152,
                                               ln1g + l * D_, ln1b + l * D_);

        gemm_bf<1, 1, 1, 128><<<dim3(32, 16), 256, 0, stream>>>(
            xcb, Wff1T, bff1 + (size_t)l * DI_, nullptr, ff1ob, nullptr, nullptr, B_ * Q_, 4096, 1024);

        gemm_bf<1, 0, 0, 64, 2><<<dim3(16, 16, 2), 256, 0, stream>>>(
            ff1ob, Wff2T, bff2 + (size_t)l * D_, addbuf, nullptr, nullptr, nullptr, B_ * Q_, 1024, 4096);

        ln_kernel<<<B_ * Q_, 256, 0, stream>>>(xc, xcb, addbuf, addbuf + 2097152,
                                               ln2g + l * D_, ln2b + l * D_);
    }
}

// Round 12
// 970.045 us; speedup vs baseline: 1.0814x; 1.0814x over previous
//
#include <hip/hip_runtime.h>
#include <math.h>

#define L_  4
#define B_  2
#define Q_  1024
#define M_  1024
#define D_  1024
#define H_  16
#define DH_ 64
#define DI_ 4096
#define KL_ (M_ + Q_)   // 2048

typedef __attribute__((ext_vector_type(8))) short short8v;  // 8 bf16 (4 VGPRs)
typedef __attribute__((ext_vector_type(4))) float f32x4;

__device__ __forceinline__ short f2bf(float f) {
    union { float f; unsigned u; } x; x.f = f;
    return (short)((x.u + 0x7FFFu + ((x.u >> 16) & 1)) >> 16);  // RNE
}
__device__ __forceinline__ unsigned pack2bf(float a, float b) {
    return (unsigned)(unsigned short)f2bf(a) | ((unsigned)(unsigned short)f2bf(b) << 16);
}
__device__ __forceinline__ float bf2f(unsigned short u) {
    union { unsigned u; float f; } x; x.u = (unsigned)u << 16; return x.f;
}
__device__ __forceinline__ unsigned cvtpk(float lo, float hi) {
    unsigned r;
    asm("v_cvt_pk_bf16_f32 %0, %1, %2" : "=v"(r) : "v"(lo), "v"(hi));
    return r;
}
__device__ __forceinline__ void gload_lds16(const short* g, short* l) {
    __builtin_amdgcn_global_load_lds((const __attribute__((address_space(1))) unsigned int*)(const void*)g,
                                     (__attribute__((address_space(3))) unsigned int*)(void*)l, 16, 0, 0);
}
// XOR swizzle key (in shorts) for stride-64-short LDS tiles
__device__ __forceinline__ int swz(int row) {
    return ((row & 7) ^ ((row >> 3) & 7)) << 3;
}
// k-permutation for the PV contraction (applied to BOTH P and V_T k index)
__device__ __forceinline__ int kperm(int k) {
    return 4 * (k & 15) + (k >> 4);
}

// ---------------- positional embedding p[KL][D] (bf16) ----------------
__global__ __launch_bounds__(256) void pos_emb_bf(short* __restrict__ p) {
    int idx = blockIdx.x * 256 + threadIdx.x;
    int k = idx >> 10;
    int i = idx & (D_ - 1);
    float pos = (float)(KL_ - 1 - k);
    int j = (i < D_ / 2) ? i : (i - D_ / 2);
    float invf = powf(10000.0f, -((float)(2 * j) / (float)D_));
    float ang = pos * invf;
    p[idx] = f2bf((i < D_ / 2) ? sinf(ang) : cosf(ang));
}

// ---------------- concat memory[l] and x into xmemb [B][KL][D] bf16 ----------------
__global__ __launch_bounds__(256) void concat_bf(short* __restrict__ xmemb,
                                                 const float* __restrict__ mem_l,
                                                 const float* __restrict__ xc) {
    int idx = blockIdx.x * 256 + threadIdx.x;
    int d = idx & (D_ - 1);
    int k = (idx >> 10) & (KL_ - 1);
    int b = idx >> 21;
    float v = (k < M_) ? mem_l[((size_t)(b * M_ + k)) * D_ + d]
                       : xc[((size_t)(b * Q_ + (k - M_))) * D_ + d];
    xmemb[idx] = f2bf(v);
}

// ---------------- tiled transpose + f32->bf16: in[K][N] -> out[N][K] ----------------
__global__ __launch_bounds__(256) void transp_bf(const float* __restrict__ in,
                                                 short* __restrict__ out,
                                                 int K, int N) {
    __shared__ float t[32][33];
    int r = threadIdx.x >> 3, c4 = (threadIdx.x & 7) * 4;
    float4 v = *(const float4*)(in + (size_t)(blockIdx.y * 32 + r) * N + blockIdx.x * 32 + c4);
    t[r][c4 + 0] = v.x; t[r][c4 + 1] = v.y; t[r][c4 + 2] = v.z; t[r][c4 + 3] = v.w;
    __syncthreads();
    uint2 o;
    o.x = pack2bf(t[c4 + 0][r], t[c4 + 1][r]);
    o.y = pack2bf(t[c4 + 2][r], t[c4 + 3][r]);
    *(uint2*)(out + (size_t)(blockIdx.x * 32 + r) * K + blockIdx.y * 32 + c4) = o;
}

// ---------------- bf16 MFMA GEMM: C[M,N] = A[M,K] @ BT[N,K]^T ----------------
// 128xTN tile, BK=32, 4 waves. KS=2: blockIdx.z halves K (partial Cf planes).
// QKVG=1: flat 640-wg grid for the fused QKV GEMM that skips the dead
// (Q-cols x memory-rows) quadrant: id<512 -> KV tiles (cols 1024..3071, all rows);
// id>=512 -> Q tiles (cols 0..1023, x-row tiles only: 8..15 and 24..31).
template <int BIAS, int RELU, int OMODE, int TN, int KS = 1, int QKVG = 0>
__global__ __launch_bounds__(256, 2) void gemm_bf(const short* __restrict__ A,
                                                  const short* __restrict__ BT,
                                                  const float* __restrict__ bias,
                                                  float* __restrict__ Cf,
                                                  short* __restrict__ C0,
                                                  short* __restrict__ C1,
                                                  short* __restrict__ C2,
                                                  int M, int N, int K) {
    __shared__ short A_s[128 * 32];
    __shared__ short B_s[TN * 32];
    const int tid = threadIdx.x;
    const int lane = tid & 63, w = tid >> 6;
    const int l15 = lane & 15, l4 = lane >> 4;
    constexpr int MF = (TN == 128) ? 4 : 2;
    const int wr = (TN == 128) ? (w >> 1) : w;
    const int wc = (TN == 128) ? (w & 1) : 0;
    const int arow0 = 32 * ((TN == 128) ? 2 * wr : w);
    const int brow0 = (TN == 128) ? 64 * wc : 0;
    int row0, col0;
    if constexpr (QKVG) {
        int id = blockIdx.x;
        if (id < 512) {                     // KV: 16 col-tiles x 32 row-tiles
            col0 = 1024 + (id & 15) * 128;
            row0 = (id >> 4) * 128;
        } else {                            // Q: 8 col-tiles x 16 x-row tiles
            int t2 = id - 512;
            col0 = (t2 & 7) * 128;
            int rt = t2 >> 3;               // 0..15
            rt = (rt < 8) ? (rt + 8) : (rt + 16);   // x rows: tiles 8..15, 24..31
            row0 = rt * 128;
        }
    } else {
        row0 = blockIdx.y * 128;
        col0 = blockIdx.x * TN;
    }
    const int kz = (KS == 2) ? blockIdx.z : 0;
    const int Kh = (KS == 2) ? (K >> 1) : K;
    const int kb = kz * Kh;

    const int lrow = lane >> 2;
    const int lk = (lane & 3) * 8;
    const short* Ag = A + (size_t)(row0 + 32 * w) * K;
    const short* Bg = BT + (size_t)(col0 + ((TN == 128) ? 32 : 16) * w) * K;

    f32x4 acc[MF][4] = {};

    for (int k0 = kb; k0 < kb + Kh; k0 += 32) {
        __syncthreads();
        gload_lds16(Ag + (size_t)lrow * K + k0 + lk,        &A_s[(32 * w) * 32]);
        gload_lds16(Ag + (size_t)(16 + lrow) * K + k0 + lk, &A_s[(32 * w + 16) * 32]);
        if (TN == 128) {
            gload_lds16(Bg + (size_t)lrow * K + k0 + lk,        &B_s[(32 * w) * 32]);
            gload_lds16(Bg + (size_t)(16 + lrow) * K + k0 + lk, &B_s[(32 * w + 16) * 32]);
        } else {
            gload_lds16(Bg + (size_t)lrow * K + k0 + lk,        &B_s[(16 * w) * 32]);
        }
        __syncthreads();
        short8v a[MF], bfr[4];
#pragma unroll
        for (int m = 0; m < MF; m++) a[m] = *(const short8v*)&A_s[(arow0 + 16 * m + l15) * 32 + 8 * l4];
#pragma unroll
        for (int n = 0; n < 4; n++) bfr[n] = *(const short8v*)&B_s[(brow0 + 16 * n + l15) * 32 + 8 * l4];
#pragma unroll
        for (int m = 0; m < MF; m++)
#pragma unroll
            for (int n = 0; n < 4; n++)
                acc[m][n] = __builtin_amdgcn_mfma_f32_16x16x32_bf16(a[m], bfr[n], acc[m][n], 0, 0, 0);
    }

    float* Cfz = Cf + (size_t)kz * M * N;
#pragma unroll
    for (int n = 0; n < 4; n++) {
        int col = col0 + brow0 + 16 * n + l15;
        float bv = (BIAS && (KS == 1 || kz == 0)) ? bias[col] : 0.0f;
#pragma unroll
        for (int m = 0; m < MF; m++) {
#pragma unroll
            for (int r = 0; r < 4; r++) {
                int row = row0 + arow0 + 16 * m + 4 * l4 + r;
                float v = acc[m][n][r] + bv;
                if (RELU) v = fmaxf(v, 0.0f);
                if (OMODE == 0) {
                    Cfz[(size_t)row * N + col] = v;
                } else if (OMODE == 1) {
                    C0[(size_t)row * N + col] = f2bf(v);
                } else {
                    int part = col >> 10, cc = col & 1023;
                    short* dst = part == 0 ? C0 : (part == 1 ? C1 : C2);
                    dst[(size_t)row * 1024 + cc] = f2bf(v);
                }
            }
        }
    }
}

// ---------------- MFMA fused attention v6 + kperm P/V path ----------------
// 512 blocks = (b, h, 64 q-rows). XCD pin: xcd=wg&7 serves h={2xcd,2xcd+1} x b.
// Double-buffered K/V tiles + 256-row R ring. AC/BD MFMA for tile t+1 issued BEFORE
// softmax(t). Defer-max (THR=8), lane-partial l, mask only on final tile.
// PV k-dim stored permuted (kperm) in BOTH P and V_T: P writes become 1 b64/row.
__global__ __launch_bounds__(256, 2) void attn_mfma(const short* __restrict__ qbf,
                                                    const short* __restrict__ kbf,
                                                    const short* __restrict__ vbf,
                                                    const short* __restrict__ rbh,
                                                    const float* __restrict__ rwb,
                                                    const float* __restrict__ rrb,
                                                    short* __restrict__ attnob) {
    __shared__ short K_s[2][64 * 64];
    __shared__ short V_T[2][64 * 64];   // V_T[d][kperm(k)], swizzled
    __shared__ short R_s[256 * 64];     // ring: phys = logical & 255
    __shared__ short P_s[4][16 * 64];   // per-wave P, k-permuted, swizzled

    const int tid = threadIdx.x;
    const int lane = tid & 63, w = tid >> 6;
    const int l15 = lane & 15, l4 = lane >> 4;
    const int lr8 = lane >> 3, oct = lane & 7;
    const int d0 = (tid & 7) * 8;

    // ---- XCD-pinned decode (512 blocks: xcd(8) x qp(16) x bl(4)) ----
    const int wg = blockIdx.x;
    const int xcd = wg & 7;
    const int qp = (wg >> 3) & 15;
    const int bl = (wg >> 7) & 3;
    const int h = xcd * 2 + (bl & 1);
    const int b = bl >> 1;
    const int qi = (qp & 1) ? (15 - (qp >> 1)) : (qp >> 1);   // work-pairing
    const int q0 = qi * 64;
    const int nt = qi + 17;
    const int jbase0 = (Q_ - 64) - q0;   // logical R row 0 -> global j

    // ---- Q frags: direct per-lane load + bias fuse (qbf [B*KL], x rows) ----
    size_t qrow = ((size_t)(b * KL_ + M_ + q0 + 16 * w + l15)) * 1024 + h * 64;
    union U8 { uint4 u; unsigned short us[8]; };
    U8 qa, qb2;
    qa.u  = *(const uint4*)(qbf + qrow + 8 * l4);
    qb2.u = *(const uint4*)(qbf + qrow + 32 + 8 * l4);
    short8v qwf0, qwf1, qrf0, qrf1;
#pragma unroll
    for (int i = 0; i < 8; i++) {
        float qv0 = bf2f(qa.us[i]), qv1 = bf2f(qb2.us[i]);
        int c0 = h * 64 + 8 * l4 + i, c1 = c0 + 32;
        qwf0[i] = f2bf(qv0 + rwb[c0]); qwf1[i] = f2bf(qv1 + rwb[c1]);
        qrf0[i] = f2bf(qv0 + rrb[c0]); qrf1[i] = f2bf(qv1 + rrb[c1]);
    }

    // ---- prologue: K(0),K(1) -> K_s, R logical [0,256) -> ring, V(0) -> V_T[0] ----
#pragma unroll
    for (int c = 0; c < 2; c++) {
        int R0 = 16 * w + 8 * c;
        int row = R0 + lr8;
        gload_lds16(kbf + ((size_t)(b * KL_) + row) * 1024 + h * 64 + ((oct * 8) ^ swz(row)),
                    &K_s[0][R0 * 64]);
        gload_lds16(kbf + ((size_t)(b * KL_) + 64 + row) * 1024 + h * 64 + ((oct * 8) ^ swz(row)),
                    &K_s[1][R0 * 64]);
    }
#pragma unroll
    for (int c = 0; c < 8; c++) {
        int R0 = 64 * w + 8 * c;
        int row = R0 + lr8;
        int jl = jbase0 + row;   // < KL
        gload_lds16(rbh + (size_t)jl * 1024 + h * 64 + ((oct * 8) ^ swz(row)),
                    &R_s[R0 * 64]);
    }
    {
        U8 cv0[2];
#pragma unroll
        for (int it = 0; it < 2; it++) {
            int rr = (tid + it * 256) >> 3;
            cv0[it].u = *(const uint4*)(vbf + ((size_t)(b * KL_) + rr) * 1024 + h * 64 + d0);
        }
#pragma unroll
        for (int it = 0; it < 2; it++) {
            int rr = (tid + it * 256) >> 3;
            int kp = kperm(rr);
#pragma unroll
            for (int i = 0; i < 8; i++)
                V_T[0][(d0 + i) * 64 + (kp ^ swz(d0 + i))] = (short)cv0[it].us[i];
        }
    }
    asm volatile("s_waitcnt vmcnt(0) lgkmcnt(0)" ::: "memory");
    __builtin_amdgcn_sched_barrier(0);
    __builtin_amdgcn_s_barrier();
    __builtin_amdgcn_sched_barrier(0);

    f32x4 o[4];
    float m_r[4], l_p[4];
#pragma unroll
    for (int j = 0; j < 4; j++) o[j] = (f32x4){0.f, 0.f, 0.f, 0.f};
#pragma unroll
    for (int r = 0; r < 4; r++) { m_r[r] = -1e30f; l_p[r] = 0.0f; }

    int sl[4];
#pragma unroll
    for (int r = 0; r < 4; r++)
        sl[r] = (lane & 48) | ((l15 + 15 - (4 * l4 + r)) & 15);

    short* P_w = &P_s[w][0];
    const int rbase = 16 * (3 - w);

    // ---- pre-compute ac/zf for tile 0 ----
    f32x4 acA[4], zfA[5], acB[4], zfB[5];
#pragma unroll
    for (int j = 0; j < 4; j++) {
        int kk = 16 * j + l15, sz = swz(kk);
        short8v b0 = *(const short8v*)&K_s[0][kk * 64 + ((8 * l4) ^ sz)];
        short8v b1 = *(const short8v*)&K_s[0][kk * 64 + ((32 + 8 * l4) ^ sz)];
        f32x4 z = {0.f, 0.f, 0.f, 0.f};
        z = __builtin_amdgcn_mfma_f32_16x16x32_bf16(qwf0, b0, z, 0, 0, 0);
        z = __builtin_amdgcn_mfma_f32_16x16x32_bf16(qwf1, b1, z, 0, 0, 0);
        acA[j] = z;
    }
#pragma unroll
    for (int jb = 0; jb < 5; jb++) {
        int rp = (rbase + 16 * jb + l15) & 255;
        int sz = swz(rp);
        short8v b0 = *(const short8v*)&R_s[rp * 64 + ((8 * l4) ^ sz)];
        short8v b1 = *(const short8v*)&R_s[rp * 64 + ((32 + 8 * l4) ^ sz)];
        f32x4 z = {0.f, 0.f, 0.f, 0.f};
        z = __builtin_amdgcn_mfma_f32_16x16x32_bf16(qrf0, b0, z, 0, 0, 0);
        z = __builtin_amdgcn_mfma_f32_16x16x32_bf16(qrf1, b1, z, 0, 0, 0);
        zfA[jb] = z;
    }

    auto body = [&](f32x4 (&ac)[4], f32x4 (&zf)[5], f32x4 (&acn)[4], f32x4 (&zfn)[5], int t)
        __attribute__((always_inline)) {
        const int cb = t & 1, nb = (t + 1) & 1;
        // ---- (a) issue next loads ----
        uint4 pv2[2];
        if (t + 1 < nt) {
#pragma unroll
            for (int it = 0; it < 2; it++) {
                int rr = (tid + it * 256) >> 3;
                pv2[it] = *(const uint4*)(vbf + ((size_t)(b * KL_) + 64 * (t + 1) + rr) * 1024 + h * 64 + d0);
            }
        }
        if (t + 2 < nt) {
#pragma unroll
            for (int c = 0; c < 2; c++) {
                int R0 = 16 * w + 8 * c;
                int row = R0 + lr8;
                gload_lds16(kbf + ((size_t)(b * KL_) + 64 * (t + 2) + row) * 1024 + h * 64 + ((oct * 8) ^ swz(row)),
                            &K_s[cb][R0 * 64]);
            }
            // R ring chunk: logical [64t+256, 64t+320)
#pragma unroll
            for (int c = 0; c < 2; c++) {
                int R0 = 16 * w + 8 * c;
                int l0 = 64 * t + 256 + R0 + lr8;
                int ph = l0 & 255;
                int jl = jbase0 + l0;
                if (jl > KL_ - 1) jl = KL_ - 1;
                gload_lds16(rbh + (size_t)jl * 1024 + h * 64 + ((oct * 8) ^ swz(ph)),
                            &R_s[((64 * t + 256 + R0) & 255) * 64]);
            }
        }
        __builtin_amdgcn_sched_barrier(0);   // keep load issues ahead

        // ---- (b) MFMA for tile t+1 (overlaps softmax(t) below) ----
        if (t + 1 < nt) {
            __builtin_amdgcn_s_setprio(1);
#pragma unroll
            for (int j = 0; j < 4; j++) {
                int kk = 16 * j + l15, sz = swz(kk);
                short8v b0 = *(const short8v*)&K_s[nb][kk * 64 + ((8 * l4) ^ sz)];
                short8v b1 = *(const short8v*)&K_s[nb][kk * 64 + ((32 + 8 * l4) ^ sz)];
                f32x4 z = {0.f, 0.f, 0.f, 0.f};
                z = __builtin_amdgcn_mfma_f32_16x16x32_bf16(qwf0, b0, z, 0, 0, 0);
                z = __builtin_amdgcn_mfma_f32_16x16x32_bf16(qwf1, b1, z, 0, 0, 0);
                acn[j] = z;
            }
#pragma unroll
            for (int jb = 0; jb < 5; jb++) {
                int rp = (64 * (t + 1) + rbase + 16 * jb + l15) & 255;
                int sz = swz(rp);
                short8v b0 = *(const short8v*)&R_s[rp * 64 + ((8 * l4) ^ sz)];
                short8v b1 = *(const short8v*)&R_s[rp * 64 + ((32 + 8 * l4) ^ sz)];
                f32x4 z = {0.f, 0.f, 0.f, 0.f};
                z = __builtin_amdgcn_mfma_f32_16x16x32_bf16(qrf0, b0, z, 0, 0, 0);
                z = __builtin_amdgcn_mfma_f32_16x16x32_bf16(qrf1, b1, z, 0, 0, 0);
                zfn[jb] = z;
            }
            __builtin_amdgcn_s_setprio(0);
        }

        // ---- (c) softmax(t): dedup BD shuffles, defer-max, lane-partial l ----
        float sv[4][4], lmax[4];
#pragma unroll
        for (int r = 0; r < 4; r++) {
            int row = 4 * l4 + r;
            float bq[5];
#pragma unroll
            for (int s = 0; s < 5; s++) bq[s] = __shfl(zf[s][r], sl[r]);
#pragma unroll
            for (int j = 0; j < 4; j++) {
                float bd = (l15 > row) ? bq[j + 1] : bq[j];
                sv[j][r] = (ac[j][r] + bd) * 0.125f;
            }
        }
        if (t == nt - 1) {   // only the final tile has masked elements
#pragma unroll
            for (int j = 0; j < 4; j++)
#pragma unroll
                for (int r = 0; r < 4; r++)
                    if (64 * t + 16 * j + l15 > q0 + 16 * w + 4 * l4 + r + M_) sv[j][r] = -1e30f;
        }
#pragma unroll
        for (int r = 0; r < 4; r++) lmax[r] = fmaxf(fmaxf(sv[0][r], sv[1][r]), fmaxf(sv[2][r], sv[3][r]));
        bool ok = true;
#pragma unroll
        for (int r = 0; r < 4; r++) ok = ok && (lmax[r] <= m_r[r] + 8.0f);
        if (!__all(ok)) {
#pragma unroll
            for (int r = 0; r < 4; r++) {
                float v = lmax[r];
                v = fmaxf(v, __shfl_xor(v, 1));
                v = fmaxf(v, __shfl_xor(v, 2));
                v = fmaxf(v, __shfl_xor(v, 4));
                v = fmaxf(v, __shfl_xor(v, 8));
                float mnew = fmaxf(m_r[r], v);
                float c = __expf(m_r[r] - mnew);
                m_r[r] = mnew;
                l_p[r] *= c;
#pragma unroll
                for (int jd = 0; jd < 4; jd++) o[jd][r] *= c;
            }
        }
#pragma unroll
        for (int j = 0; j < 4; j++)
#pragma unroll
            for (int r = 0; r < 4; r++) {
                float pp = __expf(sv[j][r] - m_r[r]);
                sv[j][r] = pp;
                l_p[r] += pp;
            }

        // ---- (d) P -> per-wave swizzled LDS (k-permuted, 1 b64/row) -> A-frags; PV ----
#pragma unroll
        for (int r = 0; r < 4; r++) {
            int row = 4 * l4 + r;
            uint2 pv;
            pv.x = cvtpk(sv[0][r], sv[1][r]);
            pv.y = cvtpk(sv[2][r], sv[3][r]);
            *(uint2*)&P_w[row * 64 + ((4 * l15) ^ swz(row))] = pv;
        }
        int szp = swz(l15);
        short8v pa0 = *(const short8v*)&P_w[l15 * 64 + ((8 * l4) ^ szp)];
        short8v pa1 = *(const short8v*)&P_w[l15 * 64 + ((32 + 8 * l4) ^ szp)];
        __builtin_amdgcn_s_setprio(1);
#pragma unroll
        for (int jd = 0; jd < 4; jd++) {
            int dd = 16 * jd + l15, sz = swz(dd);
            short8v v0 = *(const short8v*)&V_T[cb][dd * 64 + ((8 * l4) ^ sz)];
            short8v v1 = *(const short8v*)&V_T[cb][dd * 64 + ((32 + 8 * l4) ^ sz)];
            o[jd] = __builtin_amdgcn_mfma_f32_16x16x32_bf16(pa0, v0, o[jd], 0, 0, 0);
            o[jd] = __builtin_amdgcn_mfma_f32_16x16x32_bf16(pa1, v1, o[jd], 0, 0, 0);
        }
        __builtin_amdgcn_s_setprio(0);

        // ---- (e) write V(t+1) into V_T[nb] (k-permuted) ----
        if (t + 1 < nt) {
#pragma unroll
            for (int it = 0; it < 2; it++) {
                int rr = (tid + it * 256) >> 3;
                int kp = kperm(rr);
                U8 cv; cv.u = pv2[it];
#pragma unroll
                for (int i = 0; i < 8; i++)
                    V_T[nb][(d0 + i) * 64 + (kp ^ swz(d0 + i))] = (short)cv.us[i];
            }
            // ---- (f) single per-tile drain + barrier ----
            asm volatile("s_waitcnt vmcnt(0) lgkmcnt(0)" ::: "memory");
            __builtin_amdgcn_sched_barrier(0);
            __builtin_amdgcn_s_barrier();
            __builtin_amdgcn_sched_barrier(0);
        }
    };

    int t = 0;
    while (t < nt) {
        body(acA, zfA, acB, zfB, t); t++;
        if (t >= nt) break;
        body(acB, zfB, acA, zfA, t); t++;
    }

    // ---- final l reduce + normalize + store ----
    float l_r[4];
#pragma unroll
    for (int r = 0; r < 4; r++) {
        float v = l_p[r];
        v += __shfl_xor(v, 1);
        v += __shfl_xor(v, 2);
        v += __shfl_xor(v, 4);
        v += __shfl_xor(v, 8);
        l_r[r] = v;
    }
#pragma unroll
    for (int jd = 0; jd < 4; jd++) {
#pragma unroll
        for (int r = 0; r < 4; r++) {
            int qg = q0 + 16 * w + 4 * l4 + r;
            int dv = 16 * jd + l15;
            attnob[((size_t)(b * Q_ + qg)) * (H_ * DH_) + h * 64 + dv] = f2bf(o[jd][r] / l_r[r]);
        }
    }
}

// ---------------- layernorm: x = LN(x + a1 + a2) * g + b ; dual f32+bf16 out ----------------
__global__ __launch_bounds__(256) void ln_kernel(float* __restrict__ x,
                                                 short* __restrict__ xb,
                                                 const float* __restrict__ a1,
                                                 const float* __restrict__ a2,
                                                 const float* __restrict__ g,
                                                 const float* __restrict__ bb) {
    __shared__ float red[8];
    int row = blockIdx.x;
    int tid = threadIdx.x;
    float4 xv = ((const float4*)(x + (size_t)row * D_))[tid];
    float4 v1 = ((const float4*)(a1 + (size_t)row * D_))[tid];
    float4 v2 = ((const float4*)(a2 + (size_t)row * D_))[tid];
    float4 v;
    v.x = xv.x + v1.x + v2.x; v.y = xv.y + v1.y + v2.y;
    v.z = xv.z + v1.z + v2.z; v.w = xv.w + v1.w + v2.w;
    float s = v.x + v.y + v.z + v.w;
#pragma unroll
    for (int off = 32; off; off >>= 1) s += __shfl_xor(s, off);
    if ((tid & 63) == 0) red[tid >> 6] = s;
    __syncthreads();
    float mu = (red[0] + red[1] + red[2] + red[3]) * (1.0f / D_);
    float e0 = v.x - mu, e1 = v.y - mu, e2 = v.z - mu, e3 = v.w - mu;
    float sq = e0 * e0 + e1 * e1 + e2 * e2 + e3 * e3;
#pragma unroll
    for (int off = 32; off; off >>= 1) sq += __shfl_xor(sq, off);
    if ((tid & 63) == 0) red[4 + (tid >> 6)] = sq;
    __syncthreads();
    float var = (red[4] + red[5] + red[6] + red[7]) * (1.0f / D_);
    float rs = rsqrtf(var + 1e-5f);
    float4 gv = ((const float4*)g)[tid];
    float4 bv = ((const float4*)bb)[tid];
    float4 ov;
    ov.x = e0 * rs * gv.x + bv.x; ov.y = e1 * rs * gv.y + bv.y;
    ov.z = e2 * rs * gv.z + bv.z; ov.w = e3 * rs * gv.w + bv.w;
    ((float4*)(x + (size_t)row * D_))[tid] = ov;
    uint2 ob;
    ob.x = pack2bf(ov.x, ov.y);
    ob.y = pack2bf(ov.z, ov.w);
    *(uint2*)(xb + (size_t)row * D_ + tid * 4) = ob;
}

extern "C" void kernel_launch(void* const* d_in, const int* in_sizes, int n_in,
                              void* d_out, int out_size, void* d_ws, size_t ws_size,
                              hipStream_t stream) {
    const float* x    = (const float*)d_in[0];
    const float* mem  = (const float*)d_in[1];
    const float* Wqkv = (const float*)d_in[2];
    const float* Wr   = (const float*)d_in[3];
    const float* Wo   = (const float*)d_in[4];
    const float* rwb  = (const float*)d_in[5];
    const float* rrb  = (const float*)d_in[6];
    const float* ln1g = (const float*)d_in[7];
    const float* ln1b = (const float*)d_in[8];
    const float* ln2g = (const float*)d_in[9];
    const float* ln2b = (const float*)d_in[10];
    const float* Wff1 = (const float*)d_in[11];
    const float* bff1 = (const float*)d_in[12];
    const float* Wff2 = (const float*)d_in[13];
    const float* bff2 = (const float*)d_in[14];

    float* xc = (float*)d_out;

    // workspace layout (shorts unless noted)
    short* WqkvT = (short*)d_ws;              // [3072][1024]
    short* WoT   = WqkvT + 3145728;           // [1024][1024]
    short* Wff1T = WoT + 1048576;             // [4096][1024]
    short* Wff2T = Wff1T + 4194304;           // [1024][4096]
    short* WrT   = Wff2T + 4194304;           // [1024][1024]
    short* rbh   = WrT + 1048576;             // [2048][1024]
    short* xmemb = rbh + 2097152;             // [B*KL][1024]
    short* qbf   = xmemb + 4194304;           // [B*KL][1024] (x rows used)
    short* kbf   = qbf + 4194304;             // [B*KL][1024]
    short* vbf   = kbf + 4194304;             // [B*KL][1024]
    short* attnob= vbf + 4194304;             // [B*Q][1024]
    short* xcb   = attnob + 2097152;          // [B*Q][1024]
    short* ff1ob = xcb + 2097152;             // [B*Q][4096]
    float* addbuf= (float*)(ff1ob + 8388608); // [2][B*Q][1024] f32 (split-K partials)
    short* pbf   = ff1ob;                     // alias: p bf16 [2048][1024], pre-loop only

    // r = p @ W_r  (bf16 MFMA)
    transp_bf<<<dim3(32, 32), 256, 0, stream>>>(Wr, WrT, 1024, 1024);
    pos_emb_bf<<<(KL_ * D_) / 256, 256, 0, stream>>>(pbf);
    gemm_bf<0, 0, 1, 64><<<dim3(16, 16), 256, 0, stream>>>(
        pbf, WrT, nullptr, nullptr, rbh, nullptr, nullptr, KL_, 1024, 1024);

    hipMemcpyAsync(xc, x, (size_t)B_ * Q_ * D_ * sizeof(float),
                   hipMemcpyDeviceToDevice, stream);

    for (int l = 0; l < L_; l++) {
        const float* mem_l = mem + (size_t)l * B_ * M_ * D_;

        transp_bf<<<dim3(96, 32), 256, 0, stream>>>(Wqkv + (size_t)l * 3145728, WqkvT, 1024, 3072);
        transp_bf<<<dim3(32, 32), 256, 0, stream>>>(Wo + (size_t)l * 1048576, WoT, 1024, 1024);
        transp_bf<<<dim3(128, 32), 256, 0, stream>>>(Wff1 + (size_t)l * 4194304, Wff1T, 1024, 4096);
        transp_bf<<<dim3(32, 128), 256, 0, stream>>>(Wff2 + (size_t)l * 4194304, Wff2T, 4096, 1024);

        concat_bf<<<(B_ * KL_ * D_) / 256, 256, 0, stream>>>(xmemb, mem_l, xc);

        // fused QKV: flat 640-wg grid, skips Q-cols x mem-rows quadrant
        gemm_bf<0, 0, 2, 128, 1, 1><<<640, 256, 0, stream>>>(
            xmemb, WqkvT, nullptr, nullptr, qbf, kbf, vbf, B_ * KL_, 3072, 1024);

        attn_mfma<<<B_ * H_ * (Q_ / 64), 256, 0, stream>>>(
            qbf, kbf, vbf, rbh, rwb, rrb, attnob);

        gemm_bf<0, 0, 0, 64, 2><<<dim3(16, 16, 2), 256, 0, stream>>>(
            attnob, WoT, nullptr, addbuf, nullptr, nullptr, nullptr, B_ * Q_, 1024, 1024);

        ln_kernel<<<B_ * Q_, 256, 0, stream>>>(xc, xcb, addbuf, addbuf + 2097152,
                                               ln1g + l * D_, ln1b + l * D_);

        gemm_bf<1, 1, 1, 128><<<dim3(32, 16), 256, 0, stream>>>(
            xcb, Wff1T, bff1 + (size_t)l * DI_, nullptr, ff1ob, nullptr, nullptr, B_ * Q_, 4096, 1024);

        gemm_bf<1, 0, 0, 64, 2><<<dim3(16, 16, 2), 256, 0, stream>>>(
            ff1ob, Wff2T, bff2 + (size_t)l * D_, addbuf, nullptr, nullptr, nullptr, B_ * Q_, 1024, 4096);

        ln_kernel<<<B_ * Q_, 256, 0, stream>>>(xc, xcb, addbuf, addbuf + 2097152,
                                               ln2g + l * D_, ln2b + l * D_);
    }
}

// Round 13
// 949.739 us; speedup vs baseline: 1.1046x; 1.0214x over previous
//
#include <hip/hip_runtime.h>
#include <math.h>

#define L_  4
#define B_  2
#define Q_  1024
#define M_  1024
#define D_  1024
#define H_  16
#define DH_ 64
#define DI_ 4096
#define KL_ (M_ + Q_)   // 2048

typedef __attribute__((ext_vector_type(8))) short short8v;  // 8 bf16 (4 VGPRs)
typedef __attribute__((ext_vector_type(4))) float f32x4;

__device__ __forceinline__ short f2bf(float f) {
    union { float f; unsigned u; } x; x.f = f;
    return (short)((x.u + 0x7FFFu + ((x.u >> 16) & 1)) >> 16);  // RNE
}
__device__ __forceinline__ unsigned pack2bf(float a, float b) {
    return (unsigned)(unsigned short)f2bf(a) | ((unsigned)(unsigned short)f2bf(b) << 16);
}
__device__ __forceinline__ float bf2f(unsigned short u) {
    union { unsigned u; float f; } x; x.u = (unsigned)u << 16; return x.f;
}
__device__ __forceinline__ unsigned cvtpk(float lo, float hi) {
    unsigned r;
    asm("v_cvt_pk_bf16_f32 %0, %1, %2" : "=v"(r) : "v"(lo), "v"(hi));
    return r;
}
__device__ __forceinline__ void gload_lds16(const short* g, short* l) {
    __builtin_amdgcn_global_load_lds((const __attribute__((address_space(1))) unsigned int*)(const void*)g,
                                     (__attribute__((address_space(3))) unsigned int*)(void*)l, 16, 0, 0);
}
// XOR swizzle key (in shorts) for stride-64-short LDS tiles
__device__ __forceinline__ int swz(int row) {
    return ((row & 7) ^ ((row >> 3) & 7)) << 3;
}
// k-permutation for the PV contraction (applied to BOTH P and V_T k index)
__device__ __forceinline__ int kperm(int k) {
    return 4 * (k & 15) + (k >> 4);
}

// ---------------- positional embedding p[KL][D] (bf16) ----------------
__global__ __launch_bounds__(256) void pos_emb_bf(short* __restrict__ p) {
    int idx = blockIdx.x * 256 + threadIdx.x;
    int k = idx >> 10;
    int i = idx & (D_ - 1);
    float pos = (float)(KL_ - 1 - k);
    int j = (i < D_ / 2) ? i : (i - D_ / 2);
    float invf = powf(10000.0f, -((float)(2 * j) / (float)D_));
    float ang = pos * invf;
    p[idx] = f2bf((i < D_ / 2) ? sinf(ang) : cosf(ang));
}

// ---------------- tiled transpose + f32->bf16: in[K][N] -> out[N][K] ----------------
__global__ __launch_bounds__(256) void transp_bf(const float* __restrict__ in,
                                                 short* __restrict__ out,
                                                 int K, int N) {
    __shared__ float t[32][33];
    int r = threadIdx.x >> 3, c4 = (threadIdx.x & 7) * 4;
    float4 v = *(const float4*)(in + (size_t)(blockIdx.y * 32 + r) * N + blockIdx.x * 32 + c4);
    t[r][c4 + 0] = v.x; t[r][c4 + 1] = v.y; t[r][c4 + 2] = v.z; t[r][c4 + 3] = v.w;
    __syncthreads();
    uint2 o;
    o.x = pack2bf(t[c4 + 0][r], t[c4 + 1][r]);
    o.y = pack2bf(t[c4 + 2][r], t[c4 + 3][r]);
    *(uint2*)(out + (size_t)(blockIdx.x * 32 + r) * K + blockIdx.y * 32 + c4) = o;
}

// ---------------- per-layer prep: 4 weight transposes + concat, one flat grid ----------------
// id ranges: [0,3072) WqkvT (96x32 tiles), [3072,4096) WoT (32x32), [4096,8192) Wff1T
// (128x32), [8192,12288) Wff2T (32x128), [12288,16384) concat chunks (1024 elems each).
__global__ __launch_bounds__(256) void prep_layer(const float* __restrict__ Wqkv_l,
                                                  const float* __restrict__ Wo_l,
                                                  const float* __restrict__ Wff1_l,
                                                  const float* __restrict__ Wff2_l,
                                                  short* __restrict__ WqkvT,
                                                  short* __restrict__ WoT,
                                                  short* __restrict__ Wff1T,
                                                  short* __restrict__ Wff2T,
                                                  const float* __restrict__ mem_l,
                                                  const float* __restrict__ xc,
                                                  short* __restrict__ xmemb) {
    const int id = blockIdx.x;
    const int tid = threadIdx.x;
    if (id >= 12288) {                       // concat: 4 bf16 elems/thread
        int idx = ((id - 12288) * 256 + tid) * 4;
        int d = idx & (D_ - 1);
        int k = (idx >> 10) & (KL_ - 1);
        int b = idx >> 21;
        const float* src = (k < M_) ? (mem_l + ((size_t)(b * M_ + k)) * D_ + d)
                                    : (xc + ((size_t)(b * Q_ + (k - M_))) * D_ + d);
        float4 v = *(const float4*)src;
        uint2 o; o.x = pack2bf(v.x, v.y); o.y = pack2bf(v.z, v.w);
        *(uint2*)(xmemb + idx) = o;
        return;
    }
    // transpose tile
    const float* in; short* out; int K, N, bx, by;
    if (id < 3072)      { in = Wqkv_l; out = WqkvT; K = 1024; N = 3072; bx = id % 96;  by = id / 96; }
    else if (id < 4096) { int t2 = id - 3072; in = Wo_l;   out = WoT;   K = 1024; N = 1024; bx = t2 & 31;  by = t2 >> 5; }
    else if (id < 8192) { int t2 = id - 4096; in = Wff1_l; out = Wff1T; K = 1024; N = 4096; bx = t2 & 127; by = t2 >> 7; }
    else                { int t2 = id - 8192; in = Wff2_l; out = Wff2T; K = 4096; N = 1024; bx = t2 & 31;  by = t2 >> 5; }
    __shared__ float t[32][33];
    int r = tid >> 3, c4 = (tid & 7) * 4;
    float4 v = *(const float4*)(in + (size_t)(by * 32 + r) * N + bx * 32 + c4);
    t[r][c4 + 0] = v.x; t[r][c4 + 1] = v.y; t[r][c4 + 2] = v.z; t[r][c4 + 3] = v.w;
    __syncthreads();
    uint2 o;
    o.x = pack2bf(t[c4 + 0][r], t[c4 + 1][r]);
    o.y = pack2bf(t[c4 + 2][r], t[c4 + 3][r]);
    *(uint2*)(out + (size_t)(bx * 32 + r) * K + by * 32 + c4) = o;
}

// ---------------- bf16 MFMA GEMM: C[M,N] = A[M,K] @ BT[N,K]^T ----------------
// 128xTN tile, BK=32, 4 waves. KS=2: blockIdx.z halves K (partial Cf planes).
// QKVG=1: flat 640-wg grid for the fused QKV GEMM that skips the dead
// (Q-cols x memory-rows) quadrant.
template <int BIAS, int RELU, int OMODE, int TN, int KS = 1, int QKVG = 0>
__global__ __launch_bounds__(256, 2) void gemm_bf(const short* __restrict__ A,
                                                  const short* __restrict__ BT,
                                                  const float* __restrict__ bias,
                                                  float* __restrict__ Cf,
                                                  short* __restrict__ C0,
                                                  short* __restrict__ C1,
                                                  short* __restrict__ C2,
                                                  int M, int N, int K) {
    __shared__ short A_s[128 * 32];
    __shared__ short B_s[TN * 32];
    const int tid = threadIdx.x;
    const int lane = tid & 63, w = tid >> 6;
    const int l15 = lane & 15, l4 = lane >> 4;
    constexpr int MF = (TN == 128) ? 4 : 2;
    const int wr = (TN == 128) ? (w >> 1) : w;
    const int wc = (TN == 128) ? (w & 1) : 0;
    const int arow0 = 32 * ((TN == 128) ? 2 * wr : w);
    const int brow0 = (TN == 128) ? 64 * wc : 0;
    int row0, col0;
    if constexpr (QKVG) {
        int id = blockIdx.x;
        if (id < 512) {                     // KV: 16 col-tiles x 32 row-tiles
            col0 = 1024 + (id & 15) * 128;
            row0 = (id >> 4) * 128;
        } else {                            // Q: 8 col-tiles x 16 x-row tiles
            int t2 = id - 512;
            col0 = (t2 & 7) * 128;
            int rt = t2 >> 3;               // 0..15
            rt = (rt < 8) ? (rt + 8) : (rt + 16);   // x rows: tiles 8..15, 24..31
            row0 = rt * 128;
        }
    } else {
        row0 = blockIdx.y * 128;
        col0 = blockIdx.x * TN;
    }
    const int kz = (KS == 2) ? blockIdx.z : 0;
    const int Kh = (KS == 2) ? (K >> 1) : K;
    const int kb = kz * Kh;

    const int lrow = lane >> 2;
    const int lk = (lane & 3) * 8;
    const short* Ag = A + (size_t)(row0 + 32 * w) * K;
    const short* Bg = BT + (size_t)(col0 + ((TN == 128) ? 32 : 16) * w) * K;

    f32x4 acc[MF][4] = {};

    for (int k0 = kb; k0 < kb + Kh; k0 += 32) {
        __syncthreads();
        gload_lds16(Ag + (size_t)lrow * K + k0 + lk,        &A_s[(32 * w) * 32]);
        gload_lds16(Ag + (size_t)(16 + lrow) * K + k0 + lk, &A_s[(32 * w + 16) * 32]);
        if (TN == 128) {
            gload_lds16(Bg + (size_t)lrow * K + k0 + lk,        &B_s[(32 * w) * 32]);
            gload_lds16(Bg + (size_t)(16 + lrow) * K + k0 + lk, &B_s[(32 * w + 16) * 32]);
        } else {
            gload_lds16(Bg + (size_t)lrow * K + k0 + lk,        &B_s[(16 * w) * 32]);
        }
        __syncthreads();
        short8v a[MF], bfr[4];
#pragma unroll
        for (int m = 0; m < MF; m++) a[m] = *(const short8v*)&A_s[(arow0 + 16 * m + l15) * 32 + 8 * l4];
#pragma unroll
        for (int n = 0; n < 4; n++) bfr[n] = *(const short8v*)&B_s[(brow0 + 16 * n + l15) * 32 + 8 * l4];
#pragma unroll
        for (int m = 0; m < MF; m++)
#pragma unroll
            for (int n = 0; n < 4; n++)
                acc[m][n] = __builtin_amdgcn_mfma_f32_16x16x32_bf16(a[m], bfr[n], acc[m][n], 0, 0, 0);
    }

    float* Cfz = Cf + (size_t)kz * M * N;
#pragma unroll
    for (int n = 0; n < 4; n++) {
        int col = col0 + brow0 + 16 * n + l15;
        float bv = (BIAS && (KS == 1 || kz == 0)) ? bias[col] : 0.0f;
#pragma unroll
        for (int m = 0; m < MF; m++) {
#pragma unroll
            for (int r = 0; r < 4; r++) {
                int row = row0 + arow0 + 16 * m + 4 * l4 + r;
                float v = acc[m][n][r] + bv;
                if (RELU) v = fmaxf(v, 0.0f);
                if (OMODE == 0) {
                    Cfz[(size_t)row * N + col] = v;
                } else if (OMODE == 1) {
                    C0[(size_t)row * N + col] = f2bf(v);
                } else {
                    int part = col >> 10, cc = col & 1023;
                    short* dst = part == 0 ? C0 : (part == 1 ? C1 : C2);
                    dst[(size_t)row * 1024 + cc] = f2bf(v);
                }
            }
        }
    }
}

// ---------------- MFMA fused attention v6 + kperm P/V + exp2-domain softmax ----------------
// 512 blocks = (b, h, 64 q-rows). XCD pin: xcd=wg&7 serves h={2xcd,2xcd+1} x b.
// Double-buffered K/V tiles + 256-row R ring. AC/BD MFMA for tile t+1 issued BEFORE
// softmax(t). Defer-max (THR=8 nats = 11.54 log2), lane-partial l, mask only on final
// tile. Scores carried in log2 domain: s2 = (ac+bd)*(0.125*log2e), pp = exp2(s2-m2).
__global__ __launch_bounds__(256, 2) void attn_mfma(const short* __restrict__ qbf,
                                                    const short* __restrict__ kbf,
                                                    const short* __restrict__ vbf,
                                                    const short* __restrict__ rbh,
                                                    const float* __restrict__ rwb,
                                                    const float* __restrict__ rrb,
                                                    short* __restrict__ attnob) {
    __shared__ short K_s[2][64 * 64];
    __shared__ short V_T[2][64 * 64];   // V_T[d][kperm(k)], swizzled
    __shared__ short R_s[256 * 64];     // ring: phys = logical & 255
    __shared__ short P_s[4][16 * 64];   // per-wave P, k-permuted, swizzled

    const int tid = threadIdx.x;
    const int lane = tid & 63, w = tid >> 6;
    const int l15 = lane & 15, l4 = lane >> 4;
    const int lr8 = lane >> 3, oct = lane & 7;
    const int d0 = (tid & 7) * 8;
    const float SCL = 0.125f * 1.44269504089f;   // scale * log2(e)

    // ---- XCD-pinned decode (512 blocks: xcd(8) x qp(16) x bl(4)) ----
    const int wg = blockIdx.x;
    const int xcd = wg & 7;
    const int qp = (wg >> 3) & 15;
    const int bl = (wg >> 7) & 3;
    const int h = xcd * 2 + (bl & 1);
    const int b = bl >> 1;
    const int qi = (qp & 1) ? (15 - (qp >> 1)) : (qp >> 1);   // work-pairing
    const int q0 = qi * 64;
    const int nt = qi + 17;
    const int jbase0 = (Q_ - 64) - q0;   // logical R row 0 -> global j

    // ---- Q frags: direct per-lane load + bias fuse (qbf [B*KL], x rows) ----
    size_t qrow = ((size_t)(b * KL_ + M_ + q0 + 16 * w + l15)) * 1024 + h * 64;
    union U8 { uint4 u; unsigned short us[8]; };
    U8 qa, qb2;
    qa.u  = *(const uint4*)(qbf + qrow + 8 * l4);
    qb2.u = *(const uint4*)(qbf + qrow + 32 + 8 * l4);
    short8v qwf0, qwf1, qrf0, qrf1;
#pragma unroll
    for (int i = 0; i < 8; i++) {
        float qv0 = bf2f(qa.us[i]), qv1 = bf2f(qb2.us[i]);
        int c0 = h * 64 + 8 * l4 + i, c1 = c0 + 32;
        qwf0[i] = f2bf(qv0 + rwb[c0]); qwf1[i] = f2bf(qv1 + rwb[c1]);
        qrf0[i] = f2bf(qv0 + rrb[c0]); qrf1[i] = f2bf(qv1 + rrb[c1]);
    }

    // ---- prologue: K(0),K(1) -> K_s, R logical [0,256) -> ring, V(0) -> V_T[0] ----
#pragma unroll
    for (int c = 0; c < 2; c++) {
        int R0 = 16 * w + 8 * c;
        int row = R0 + lr8;
        gload_lds16(kbf + ((size_t)(b * KL_) + row) * 1024 + h * 64 + ((oct * 8) ^ swz(row)),
                    &K_s[0][R0 * 64]);
        gload_lds16(kbf + ((size_t)(b * KL_) + 64 + row) * 1024 + h * 64 + ((oct * 8) ^ swz(row)),
                    &K_s[1][R0 * 64]);
    }
#pragma unroll
    for (int c = 0; c < 8; c++) {
        int R0 = 64 * w + 8 * c;
        int row = R0 + lr8;
        int jl = jbase0 + row;   // < KL
        gload_lds16(rbh + (size_t)jl * 1024 + h * 64 + ((oct * 8) ^ swz(row)),
                    &R_s[R0 * 64]);
    }
    {
        U8 cv0[2];
#pragma unroll
        for (int it = 0; it < 2; it++) {
            int rr = (tid + it * 256) >> 3;
            cv0[it].u = *(const uint4*)(vbf + ((size_t)(b * KL_) + rr) * 1024 + h * 64 + d0);
        }
#pragma unroll
        for (int it = 0; it < 2; it++) {
            int rr = (tid + it * 256) >> 3;
            int kp = kperm(rr);
#pragma unroll
            for (int i = 0; i < 8; i++)
                V_T[0][(d0 + i) * 64 + (kp ^ swz(d0 + i))] = (short)cv0[it].us[i];
        }
    }
    asm volatile("s_waitcnt vmcnt(0) lgkmcnt(0)" ::: "memory");
    __builtin_amdgcn_sched_barrier(0);
    __builtin_amdgcn_s_barrier();
    __builtin_amdgcn_sched_barrier(0);

    f32x4 o[4];
    float m_r[4], l_p[4];
#pragma unroll
    for (int j = 0; j < 4; j++) o[j] = (f32x4){0.f, 0.f, 0.f, 0.f};
#pragma unroll
    for (int r = 0; r < 4; r++) { m_r[r] = -1e30f; l_p[r] = 0.0f; }

    int sl[4];
#pragma unroll
    for (int r = 0; r < 4; r++)
        sl[r] = (lane & 48) | ((l15 + 15 - (4 * l4 + r)) & 15);

    short* P_w = &P_s[w][0];
    const int rbase = 16 * (3 - w);

    // ---- pre-compute ac/zf for tile 0 ----
    f32x4 acA[4], zfA[5], acB[4], zfB[5];
#pragma unroll
    for (int j = 0; j < 4; j++) {
        int kk = 16 * j + l15, sz = swz(kk);
        short8v b0 = *(const short8v*)&K_s[0][kk * 64 + ((8 * l4) ^ sz)];
        short8v b1 = *(const short8v*)&K_s[0][kk * 64 + ((32 + 8 * l4) ^ sz)];
        f32x4 z = {0.f, 0.f, 0.f, 0.f};
        z = __builtin_amdgcn_mfma_f32_16x16x32_bf16(qwf0, b0, z, 0, 0, 0);
        z = __builtin_amdgcn_mfma_f32_16x16x32_bf16(qwf1, b1, z, 0, 0, 0);
        acA[j] = z;
    }
#pragma unroll
    for (int jb = 0; jb < 5; jb++) {
        int rp = (rbase + 16 * jb + l15) & 255;
        int sz = swz(rp);
        short8v b0 = *(const short8v*)&R_s[rp * 64 + ((8 * l4) ^ sz)];
        short8v b1 = *(const short8v*)&R_s[rp * 64 + ((32 + 8 * l4) ^ sz)];
        f32x4 z = {0.f, 0.f, 0.f, 0.f};
        z = __builtin_amdgcn_mfma_f32_16x16x32_bf16(qrf0, b0, z, 0, 0, 0);
        z = __builtin_amdgcn_mfma_f32_16x16x32_bf16(qrf1, b1, z, 0, 0, 0);
        zfA[jb] = z;
    }

    auto body = [&](f32x4 (&ac)[4], f32x4 (&zf)[5], f32x4 (&acn)[4], f32x4 (&zfn)[5], int t)
        __attribute__((always_inline)) {
        const int cb = t & 1, nb = (t + 1) & 1;
        // ---- (a) issue next loads ----
        uint4 pv2[2];
        if (t + 1 < nt) {
#pragma unroll
            for (int it = 0; it < 2; it++) {
                int rr = (tid + it * 256) >> 3;
                pv2[it] = *(const uint4*)(vbf + ((size_t)(b * KL_) + 64 * (t + 1) + rr) * 1024 + h * 64 + d0);
            }
        }
        if (t + 2 < nt) {
#pragma unroll
            for (int c = 0; c < 2; c++) {
                int R0 = 16 * w + 8 * c;
                int row = R0 + lr8;
                gload_lds16(kbf + ((size_t)(b * KL_) + 64 * (t + 2) + row) * 1024 + h * 64 + ((oct * 8) ^ swz(row)),
                            &K_s[cb][R0 * 64]);
            }
            // R ring chunk: logical [64t+256, 64t+320)
#pragma unroll
            for (int c = 0; c < 2; c++) {
                int R0 = 16 * w + 8 * c;
                int l0 = 64 * t + 256 + R0 + lr8;
                int ph = l0 & 255;
                int jl = jbase0 + l0;
                if (jl > KL_ - 1) jl = KL_ - 1;
                gload_lds16(rbh + (size_t)jl * 1024 + h * 64 + ((oct * 8) ^ swz(ph)),
                            &R_s[((64 * t + 256 + R0) & 255) * 64]);
            }
        }
        __builtin_amdgcn_sched_barrier(0);   // keep load issues ahead

        // ---- (b) MFMA for tile t+1 (overlaps softmax(t) below) ----
        if (t + 1 < nt) {
            __builtin_amdgcn_s_setprio(1);
#pragma unroll
            for (int j = 0; j < 4; j++) {
                int kk = 16 * j + l15, sz = swz(kk);
                short8v b0 = *(const short8v*)&K_s[nb][kk * 64 + ((8 * l4) ^ sz)];
                short8v b1 = *(const short8v*)&K_s[nb][kk * 64 + ((32 + 8 * l4) ^ sz)];
                f32x4 z = {0.f, 0.f, 0.f, 0.f};
                z = __builtin_amdgcn_mfma_f32_16x16x32_bf16(qwf0, b0, z, 0, 0, 0);
                z = __builtin_amdgcn_mfma_f32_16x16x32_bf16(qwf1, b1, z, 0, 0, 0);
                acn[j] = z;
            }
#pragma unroll
            for (int jb = 0; jb < 5; jb++) {
                int rp = (64 * (t + 1) + rbase + 16 * jb + l15) & 255;
                int sz = swz(rp);
                short8v b0 = *(const short8v*)&R_s[rp * 64 + ((8 * l4) ^ sz)];
                short8v b1 = *(const short8v*)&R_s[rp * 64 + ((32 + 8 * l4) ^ sz)];
                f32x4 z = {0.f, 0.f, 0.f, 0.f};
                z = __builtin_amdgcn_mfma_f32_16x16x32_bf16(qrf0, b0, z, 0, 0, 0);
                z = __builtin_amdgcn_mfma_f32_16x16x32_bf16(qrf1, b1, z, 0, 0, 0);
                zfn[jb] = z;
            }
            __builtin_amdgcn_s_setprio(0);
        }

        // ---- (c) softmax(t) in log2 domain ----
        float sv[4][4], lmax[4];
#pragma unroll
        for (int r = 0; r < 4; r++) {
            int row = 4 * l4 + r;
            float bq[5];
#pragma unroll
            for (int s = 0; s < 5; s++) bq[s] = __shfl(zf[s][r], sl[r]);
#pragma unroll
            for (int j = 0; j < 4; j++) {
                float bd = (l15 > row) ? bq[j + 1] : bq[j];
                sv[j][r] = (ac[j][r] + bd) * SCL;
            }
        }
        if (t == nt - 1) {   // only the final tile has masked elements
#pragma unroll
            for (int j = 0; j < 4; j++)
#pragma unroll
                for (int r = 0; r < 4; r++)
                    if (64 * t + 16 * j + l15 > q0 + 16 * w + 4 * l4 + r + M_) sv[j][r] = -1e30f;
        }
#pragma unroll
        for (int r = 0; r < 4; r++) lmax[r] = fmaxf(fmaxf(sv[0][r], sv[1][r]), fmaxf(sv[2][r], sv[3][r]));
        bool ok = true;
#pragma unroll
        for (int r = 0; r < 4; r++) ok = ok && (lmax[r] <= m_r[r] + 11.5415603f);
        if (!__all(ok)) {
#pragma unroll
            for (int r = 0; r < 4; r++) {
                float v = lmax[r];
                v = fmaxf(v, __shfl_xor(v, 1));
                v = fmaxf(v, __shfl_xor(v, 2));
                v = fmaxf(v, __shfl_xor(v, 4));
                v = fmaxf(v, __shfl_xor(v, 8));
                float mnew = fmaxf(m_r[r], v);
                float c = exp2f(m_r[r] - mnew);
                m_r[r] = mnew;
                l_p[r] *= c;
#pragma unroll
                for (int jd = 0; jd < 4; jd++) o[jd][r] *= c;
            }
        }
#pragma unroll
        for (int j = 0; j < 4; j++)
#pragma unroll
            for (int r = 0; r < 4; r++) {
                float pp = exp2f(sv[j][r] - m_r[r]);
                sv[j][r] = pp;
                l_p[r] += pp;
            }

        // ---- (d) P -> per-wave swizzled LDS (k-permuted, 1 b64/row) -> A-frags; PV ----
#pragma unroll
        for (int r = 0; r < 4; r++) {
            int row = 4 * l4 + r;
            uint2 pv;
            pv.x = cvtpk(sv[0][r], sv[1][r]);
            pv.y = cvtpk(sv[2][r], sv[3][r]);
            *(uint2*)&P_w[row * 64 + ((4 * l15) ^ swz(row))] = pv;
        }
        int szp = swz(l15);
        short8v pa0 = *(const short8v*)&P_w[l15 * 64 + ((8 * l4) ^ szp)];
        short8v pa1 = *(const short8v*)&P_w[l15 * 64 + ((32 + 8 * l4) ^ szp)];
        __builtin_amdgcn_s_setprio(1);
#pragma unroll
        for (int jd = 0; jd < 4; jd++) {
            int dd = 16 * jd + l15, sz = swz(dd);
            short8v v0 = *(const short8v*)&V_T[cb][dd * 64 + ((8 * l4) ^ sz)];
            short8v v1 = *(const short8v*)&V_T[cb][dd * 64 + ((32 + 8 * l4) ^ sz)];
            o[jd] = __builtin_amdgcn_mfma_f32_16x16x32_bf16(pa0, v0, o[jd], 0, 0, 0);
            o[jd] = __builtin_amdgcn_mfma_f32_16x16x32_bf16(pa1, v1, o[jd], 0, 0, 0);
        }
        __builtin_amdgcn_s_setprio(0);

        // ---- (e) write V(t+1) into V_T[nb] (k-permuted) ----
        if (t + 1 < nt) {
#pragma unroll
            for (int it = 0; it < 2; it++) {
                int rr = (tid + it * 256) >> 3;
                int kp = kperm(rr);
                U8 cv; cv.u = pv2[it];
#pragma unroll
                for (int i = 0; i < 8; i++)
                    V_T[nb][(d0 + i) * 64 + (kp ^ swz(d0 + i))] = (short)cv.us[i];
            }
            // ---- (f) single per-tile drain + barrier ----
            asm volatile("s_waitcnt vmcnt(0) lgkmcnt(0)" ::: "memory");
            __builtin_amdgcn_sched_barrier(0);
            __builtin_amdgcn_s_barrier();
            __builtin_amdgcn_sched_barrier(0);
        }
    };

    int t = 0;
    while (t < nt) {
        body(acA, zfA, acB, zfB, t); t++;
        if (t >= nt) break;
        body(acB, zfB, acA, zfA, t); t++;
    }

    // ---- final l reduce + normalize + store ----
    float l_r[4];
#pragma unroll
    for (int r = 0; r < 4; r++) {
        float v = l_p[r];
        v += __shfl_xor(v, 1);
        v += __shfl_xor(v, 2);
        v += __shfl_xor(v, 4);
        v += __shfl_xor(v, 8);
        l_r[r] = v;
    }
#pragma unroll
    for (int jd = 0; jd < 4; jd++) {
#pragma unroll
        for (int r = 0; r < 4; r++) {
            int qg = q0 + 16 * w + 4 * l4 + r;
            int dv = 16 * jd + l15;
            attnob[((size_t)(b * Q_ + qg)) * (H_ * DH_) + h * 64 + dv] = f2bf(o[jd][r] / l_r[r]);
        }
    }
}

// ---------------- layernorm: x = LN(x + a1 + a2) * g + b ; dual f32+bf16 out ----------------
__global__ __launch_bounds__(256) void ln_kernel(float* __restrict__ x,
                                                 short* __restrict__ xb,
                                                 const float* __restrict__ a1,
                                                 const float* __restrict__ a2,
                                                 const float* __restrict__ g,
                                                 const float* __restrict__ bb) {
    __shared__ float red[8];
    int row = blockIdx.x;
    int tid = threadIdx.x;
    float4 xv = ((const float4*)(x + (size_t)row * D_))[tid];
    float4 v1 = ((const float4*)(a1 + (size_t)row * D_))[tid];
    float4 v2 = ((const float4*)(a2 + (size_t)row * D_))[tid];
    float4 v;
    v.x = xv.x + v1.x + v2.x; v.y = xv.y + v1.y + v2.y;
    v.z = xv.z + v1.z + v2.z; v.w = xv.w + v1.w + v2.w;
    float s = v.x + v.y + v.z + v.w;
#pragma unroll
    for (int off = 32; off; off >>= 1) s += __shfl_xor(s, off);
    if ((tid & 63) == 0) red[tid >> 6] = s;
    __syncthreads();
    float mu = (red[0] + red[1] + red[2] + red[3]) * (1.0f / D_);
    float e0 = v.x - mu, e1 = v.y - mu, e2 = v.z - mu, e3 = v.w - mu;
    float sq = e0 * e0 + e1 * e1 + e2 * e2 + e3 * e3;
#pragma unroll
    for (int off = 32; off; off >>= 1) sq += __shfl_xor(sq, off);
    if ((tid & 63) == 0) red[4 + (tid >> 6)] = sq;
    __syncthreads();
    float var = (red[4] + red[5] + red[6] + red[7]) * (1.0f / D_);
    float rs = rsqrtf(var + 1e-5f);
    float4 gv = ((const float4*)g)[tid];
    float4 bv = ((const float4*)bb)[tid];
    float4 ov;
    ov.x = e0 * rs * gv.x + bv.x; ov.y = e1 * rs * gv.y + bv.y;
    ov.z = e2 * rs * gv.z + bv.z; ov.w = e3 * rs * gv.w + bv.w;
    ((float4*)(x + (size_t)row * D_))[tid] = ov;
    uint2 ob;
    ob.x = pack2bf(ov.x, ov.y);
    ob.y = pack2bf(ov.z, ov.w);
    *(uint2*)(xb + (size_t)row * D_ + tid * 4) = ob;
}

extern "C" void kernel_launch(void* const* d_in, const int* in_sizes, int n_in,
                              void* d_out, int out_size, void* d_ws, size_t ws_size,
                              hipStream_t stream) {
    const float* x    = (const float*)d_in[0];
    const float* mem  = (const float*)d_in[1];
    const float* Wqkv = (const float*)d_in[2];
    const float* Wr   = (const float*)d_in[3];
    const float* Wo   = (const float*)d_in[4];
    const float* rwb  = (const float*)d_in[5];
    const float* rrb  = (const float*)d_in[6];
    const float* ln1g = (const float*)d_in[7];
    const float* ln1b = (const float*)d_in[8];
    const float* ln2g = (const float*)d_in[9];
    const float* ln2b = (const float*)d_in[10];
    const float* Wff1 = (const float*)d_in[11];
    const float* bff1 = (const float*)d_in[12];
    const float* Wff2 = (const float*)d_in[13];
    const float* bff2 = (const float*)d_in[14];

    float* xc = (float*)d_out;

    // workspace layout (shorts unless noted)
    short* WqkvT = (short*)d_ws;              // [3072][1024]
    short* WoT   = WqkvT + 3145728;           // [1024][1024]
    short* Wff1T = WoT + 1048576;             // [4096][1024]
    short* Wff2T = Wff1T + 4194304;           // [1024][4096]
    short* WrT   = Wff2T + 4194304;           // [1024][1024]
    short* rbh   = WrT + 1048576;             // [2048][1024]
    short* xmemb = rbh + 2097152;             // [B*KL][1024]
    short* qbf   = xmemb + 4194304;           // [B*KL][1024] (x rows used)
    short* kbf   = qbf + 4194304;             // [B*KL][1024]
    short* vbf   = kbf + 4194304;             // [B*KL][1024]
    short* attnob= vbf + 4194304;             // [B*Q][1024]
    short* xcb   = attnob + 2097152;          // [B*Q][1024]
    short* ff1ob = xcb + 2097152;             // [B*Q][4096]
    float* addbuf= (float*)(ff1ob + 8388608); // [2][B*Q][1024] f32 (split-K partials)
    short* pbf   = ff1ob;                     // alias: p bf16 [2048][1024], pre-loop only

    // r = p @ W_r  (bf16 MFMA)
    transp_bf<<<dim3(32, 32), 256, 0, stream>>>(Wr, WrT, 1024, 1024);
    pos_emb_bf<<<(KL_ * D_) / 256, 256, 0, stream>>>(pbf);
    gemm_bf<0, 0, 1, 64><<<dim3(16, 16), 256, 0, stream>>>(
        pbf, WrT, nullptr, nullptr, rbh, nullptr, nullptr, KL_, 1024, 1024);

    hipMemcpyAsync(xc, x, (size_t)B_ * Q_ * D_ * sizeof(float),
                   hipMemcpyDeviceToDevice, stream);

    for (int l = 0; l < L_; l++) {
        const float* mem_l = mem + (size_t)l * B_ * M_ * D_;

        prep_layer<<<16384, 256, 0, stream>>>(
            Wqkv + (size_t)l * 3145728, Wo + (size_t)l * 1048576,
            Wff1 + (size_t)l * 4194304, Wff2 + (size_t)l * 4194304,
            WqkvT, WoT, Wff1T, Wff2T, mem_l, xc, xmemb);

        // fused QKV: flat 640-wg grid, skips Q-cols x mem-rows quadrant
        gemm_bf<0, 0, 2, 128, 1, 1><<<640, 256, 0, stream>>>(
            xmemb, WqkvT, nullptr, nullptr, qbf, kbf, vbf, B_ * KL_, 3072, 1024);

        attn_mfma<<<B_ * H_ * (Q_ / 64), 256, 0, stream>>>(
            qbf, kbf, vbf, rbh, rwb, rrb, attnob);

        gemm_bf<0, 0, 0, 64, 2><<<dim3(16, 16, 2), 256, 0, stream>>>(
            attnob, WoT, nullptr, addbuf, nullptr, nullptr, nullptr, B_ * Q_, 1024, 1024);

        ln_kernel<<<B_ * Q_, 256, 0, stream>>>(xc, xcb, addbuf, addbuf + 2097152,
                                               ln1g + l * D_, ln1b + l * D_);

        gemm_bf<1, 1, 1, 128><<<dim3(32, 16), 256, 0, stream>>>(
            xcb, Wff1T, bff1 + (size_t)l * DI_, nullptr, ff1ob, nullptr, nullptr, B_ * Q_, 4096, 1024);

        gemm_bf<1, 0, 0, 64, 2><<<dim3(16, 16, 2), 256, 0, stream>>>(
            ff1ob, Wff2T, bff2 + (size_t)l * D_, addbuf, nullptr, nullptr, nullptr, B_ * Q_, 1024, 4096);

        ln_kernel<<<B_ * Q_, 256, 0, stream>>>(xc, xcb, addbuf, addbuf + 2097152,
                                               ln2g + l * D_, ln2b + l * D_);
    }
}

// Round 14
// 934.677 us; speedup vs baseline: 1.1224x; 1.0161x over previous
//
#include <hip/hip_runtime.h>
#include <math.h>

#define L_  4
#define B_  2
#define Q_  1024
#define M_  1024
#define D_  1024
#define H_  16
#define DH_ 64
#define DI_ 4096
#define KL_ (M_ + Q_)   // 2048

typedef __attribute__((ext_vector_type(8))) short short8v;  // 8 bf16 (4 VGPRs)
typedef __attribute__((ext_vector_type(4))) float f32x4;

__device__ __forceinline__ short f2bf(float f) {
    union { float f; unsigned u; } x; x.f = f;
    return (short)((x.u + 0x7FFFu + ((x.u >> 16) & 1)) >> 16);  // RNE
}
__device__ __forceinline__ unsigned pack2bf(float a, float b) {
    return (unsigned)(unsigned short)f2bf(a) | ((unsigned)(unsigned short)f2bf(b) << 16);
}
__device__ __forceinline__ float bf2f(unsigned short u) {
    union { unsigned u; float f; } x; x.u = (unsigned)u << 16; return x.f;
}
__device__ __forceinline__ unsigned cvtpk(float lo, float hi) {
    unsigned r;
    asm("v_cvt_pk_bf16_f32 %0, %1, %2" : "=v"(r) : "v"(lo), "v"(hi));
    return r;
}
__device__ __forceinline__ void gload_lds16(const short* g, short* l) {
    __builtin_amdgcn_global_load_lds((const __attribute__((address_space(1))) unsigned int*)(const void*)g,
                                     (__attribute__((address_space(3))) unsigned int*)(void*)l, 16, 0, 0);
}
// XOR swizzle key (in shorts) for stride-64-short LDS tiles
__device__ __forceinline__ int swz(int row) {
    return ((row & 7) ^ ((row >> 3) & 7)) << 3;
}
// k-permutation for the PV contraction (applied to BOTH P and V_T k index)
__device__ __forceinline__ int kperm(int k) {
    return 4 * (k & 15) + (k >> 4);
}

// ---------------- positional embedding p[KL][D] (bf16) ----------------
__global__ __launch_bounds__(256) void pos_emb_bf(short* __restrict__ p) {
    int idx = blockIdx.x * 256 + threadIdx.x;
    int k = idx >> 10;
    int i = idx & (D_ - 1);
    float pos = (float)(KL_ - 1 - k);
    int j = (i < D_ / 2) ? i : (i - D_ / 2);
    float invf = powf(10000.0f, -((float)(2 * j) / (float)D_));
    float ang = pos * invf;
    p[idx] = f2bf((i < D_ / 2) ? sinf(ang) : cosf(ang));
}

// ---------------- tiled transpose + f32->bf16: in[K][N] -> out[N][K] ----------------
__global__ __launch_bounds__(256) void transp_bf(const float* __restrict__ in,
                                                 short* __restrict__ out,
                                                 int K, int N) {
    __shared__ float t[32][33];
    int r = threadIdx.x >> 3, c4 = (threadIdx.x & 7) * 4;
    float4 v = *(const float4*)(in + (size_t)(blockIdx.y * 32 + r) * N + blockIdx.x * 32 + c4);
    t[r][c4 + 0] = v.x; t[r][c4 + 1] = v.y; t[r][c4 + 2] = v.z; t[r][c4 + 3] = v.w;
    __syncthreads();
    uint2 o;
    o.x = pack2bf(t[c4 + 0][r], t[c4 + 1][r]);
    o.y = pack2bf(t[c4 + 2][r], t[c4 + 3][r]);
    *(uint2*)(out + (size_t)(blockIdx.x * 32 + r) * K + blockIdx.y * 32 + c4) = o;
}

// ---------------- per-layer prep: 4 weight transposes + concat, one flat grid ----------------
// id ranges: [0,3072) WqkvT (96x32 tiles), [3072,4096) WoT (32x32), [4096,8192) Wff1T
// (128x32), [8192,12288) Wff2T (32x128), [12288,16384) concat chunks (1024 elems each).
__global__ __launch_bounds__(256) void prep_layer(const float* __restrict__ Wqkv_l,
                                                  const float* __restrict__ Wo_l,
                                                  const float* __restrict__ Wff1_l,
                                                  const float* __restrict__ Wff2_l,
                                                  short* __restrict__ WqkvT,
                                                  short* __restrict__ WoT,
                                                  short* __restrict__ Wff1T,
                                                  short* __restrict__ Wff2T,
                                                  const float* __restrict__ mem_l,
                                                  const float* __restrict__ xc,
                                                  short* __restrict__ xmemb) {
    const int id = blockIdx.x;
    const int tid = threadIdx.x;
    if (id >= 12288) {                       // concat: 4 bf16 elems/thread
        int idx = ((id - 12288) * 256 + tid) * 4;
        int d = idx & (D_ - 1);
        int k = (idx >> 10) & (KL_ - 1);
        int b = idx >> 21;
        const float* src = (k < M_) ? (mem_l + ((size_t)(b * M_ + k)) * D_ + d)
                                    : (xc + ((size_t)(b * Q_ + (k - M_))) * D_ + d);
        float4 v = *(const float4*)src;
        uint2 o; o.x = pack2bf(v.x, v.y); o.y = pack2bf(v.z, v.w);
        *(uint2*)(xmemb + idx) = o;
        return;
    }
    // transpose tile
    const float* in; short* out; int K, N, bx, by;
    if (id < 3072)      { in = Wqkv_l; out = WqkvT; K = 1024; N = 3072; bx = id % 96;  by = id / 96; }
    else if (id < 4096) { int t2 = id - 3072; in = Wo_l;   out = WoT;   K = 1024; N = 1024; bx = t2 & 31;  by = t2 >> 5; }
    else if (id < 8192) { int t2 = id - 4096; in = Wff1_l; out = Wff1T; K = 1024; N = 4096; bx = t2 & 127; by = t2 >> 7; }
    else                { int t2 = id - 8192; in = Wff2_l; out = Wff2T; K = 4096; N = 1024; bx = t2 & 31;  by = t2 >> 5; }
    __shared__ float t[32][33];
    int r = tid >> 3, c4 = (tid & 7) * 4;
    float4 v = *(const float4*)(in + (size_t)(by * 32 + r) * N + bx * 32 + c4);
    t[r][c4 + 0] = v.x; t[r][c4 + 1] = v.y; t[r][c4 + 2] = v.z; t[r][c4 + 3] = v.w;
    __syncthreads();
    uint2 o;
    o.x = pack2bf(t[c4 + 0][r], t[c4 + 1][r]);
    o.y = pack2bf(t[c4 + 2][r], t[c4 + 3][r]);
    *(uint2*)(out + (size_t)(bx * 32 + r) * K + by * 32 + c4) = o;
}

// ---------------- bf16 MFMA GEMM: C[M,N] = A[M,K] @ BT[N,K]^T ----------------
// 128xTN tile, BK=32, 4 waves. KS=2: blockIdx.z halves K (partial Cf planes).
// QKVG=1: flat 640-wg grid for the fused QKV GEMM that skips the dead
// (Q-cols x memory-rows) quadrant.
template <int BIAS, int RELU, int OMODE, int TN, int KS = 1, int QKVG = 0>
__global__ __launch_bounds__(256, 2) void gemm_bf(const short* __restrict__ A,
                                                  const short* __restrict__ BT,
                                                  const float* __restrict__ bias,
                                                  float* __restrict__ Cf,
                                                  short* __restrict__ C0,
                                                  short* __restrict__ C1,
                                                  short* __restrict__ C2,
                                                  int M, int N, int K) {
    __shared__ short A_s[128 * 32];
    __shared__ short B_s[TN * 32];
    const int tid = threadIdx.x;
    const int lane = tid & 63, w = tid >> 6;
    const int l15 = lane & 15, l4 = lane >> 4;
    constexpr int MF = (TN == 128) ? 4 : 2;
    const int wr = (TN == 128) ? (w >> 1) : w;
    const int wc = (TN == 128) ? (w & 1) : 0;
    const int arow0 = 32 * ((TN == 128) ? 2 * wr : w);
    const int brow0 = (TN == 128) ? 64 * wc : 0;
    int row0, col0;
    if constexpr (QKVG) {
        int id = blockIdx.x;
        if (id < 512) {                     // KV: 16 col-tiles x 32 row-tiles
            col0 = 1024 + (id & 15) * 128;
            row0 = (id >> 4) * 128;
        } else {                            // Q: 8 col-tiles x 16 x-row tiles
            int t2 = id - 512;
            col0 = (t2 & 7) * 128;
            int rt = t2 >> 3;               // 0..15
            rt = (rt < 8) ? (rt + 8) : (rt + 16);   // x rows: tiles 8..15, 24..31
            row0 = rt * 128;
        }
    } else {
        row0 = blockIdx.y * 128;
        col0 = blockIdx.x * TN;
    }
    const int kz = (KS == 2) ? blockIdx.z : 0;
    const int Kh = (KS == 2) ? (K >> 1) : K;
    const int kb = kz * Kh;

    const int lrow = lane >> 2;
    const int lk = (lane & 3) * 8;
    const short* Ag = A + (size_t)(row0 + 32 * w) * K;
    const short* Bg = BT + (size_t)(col0 + ((TN == 128) ? 32 : 16) * w) * K;

    f32x4 acc[MF][4] = {};

    for (int k0 = kb; k0 < kb + Kh; k0 += 32) {
        __syncthreads();
        gload_lds16(Ag + (size_t)lrow * K + k0 + lk,        &A_s[(32 * w) * 32]);
        gload_lds16(Ag + (size_t)(16 + lrow) * K + k0 + lk, &A_s[(32 * w + 16) * 32]);
        if (TN == 128) {
            gload_lds16(Bg + (size_t)lrow * K + k0 + lk,        &B_s[(32 * w) * 32]);
            gload_lds16(Bg + (size_t)(16 + lrow) * K + k0 + lk, &B_s[(32 * w + 16) * 32]);
        } else {
            gload_lds16(Bg + (size_t)lrow * K + k0 + lk,        &B_s[(16 * w) * 32]);
        }
        __syncthreads();
        short8v a[MF], bfr[4];
#pragma unroll
        for (int m = 0; m < MF; m++) a[m] = *(const short8v*)&A_s[(arow0 + 16 * m + l15) * 32 + 8 * l4];
#pragma unroll
        for (int n = 0; n < 4; n++) bfr[n] = *(const short8v*)&B_s[(brow0 + 16 * n + l15) * 32 + 8 * l4];
#pragma unroll
        for (int m = 0; m < MF; m++)
#pragma unroll
            for (int n = 0; n < 4; n++)
                acc[m][n] = __builtin_amdgcn_mfma_f32_16x16x32_bf16(a[m], bfr[n], acc[m][n], 0, 0, 0);
    }

    float* Cfz = Cf + (size_t)kz * M * N;
#pragma unroll
    for (int n = 0; n < 4; n++) {
        int col = col0 + brow0 + 16 * n + l15;
        float bv = (BIAS && (KS == 1 || kz == 0)) ? bias[col] : 0.0f;
#pragma unroll
        for (int m = 0; m < MF; m++) {
#pragma unroll
            for (int r = 0; r < 4; r++) {
                int row = row0 + arow0 + 16 * m + 4 * l4 + r;
                float v = acc[m][n][r] + bv;
                if (RELU) v = fmaxf(v, 0.0f);
                if (OMODE == 0) {
                    Cfz[(size_t)row * N + col] = v;
                } else if (OMODE == 1) {
                    C0[(size_t)row * N + col] = f2bf(v);
                } else {
                    int part = col >> 10, cc = col & 1023;
                    short* dst = part == 0 ? C0 : (part == 1 ? C1 : C2);
                    dst[(size_t)row * 1024 + cc] = f2bf(v);
                }
            }
        }
    }
}

// ---------------- MFMA fused attention v6 + kperm P/V path (softmax: __expf, R11-proven) ----------------
// 512 blocks = (b, h, 64 q-rows). XCD pin: xcd=wg&7 serves h={2xcd,2xcd+1} x b.
// Double-buffered K/V tiles + 256-row R ring. AC/BD MFMA for tile t+1 issued BEFORE
// softmax(t). Defer-max (THR=8), lane-partial l, mask only on final tile.
// PV k-dim stored permuted (kperm) in BOTH P and V_T: P writes become 1 b64/row.
__global__ __launch_bounds__(256, 2) void attn_mfma(const short* __restrict__ qbf,
                                                    const short* __restrict__ kbf,
                                                    const short* __restrict__ vbf,
                                                    const short* __restrict__ rbh,
                                                    const float* __restrict__ rwb,
                                                    const float* __restrict__ rrb,
                                                    short* __restrict__ attnob) {
    __shared__ short K_s[2][64 * 64];
    __shared__ short V_T[2][64 * 64];   // V_T[d][kperm(k)], swizzled
    __shared__ short R_s[256 * 64];     // ring: phys = logical & 255
    __shared__ short P_s[4][16 * 64];   // per-wave P, k-permuted, swizzled

    const int tid = threadIdx.x;
    const int lane = tid & 63, w = tid >> 6;
    const int l15 = lane & 15, l4 = lane >> 4;
    const int lr8 = lane >> 3, oct = lane & 7;
    const int d0 = (tid & 7) * 8;

    // ---- XCD-pinned decode (512 blocks: xcd(8) x qp(16) x bl(4)) ----
    const int wg = blockIdx.x;
    const int xcd = wg & 7;
    const int qp = (wg >> 3) & 15;
    const int bl = (wg >> 7) & 3;
    const int h = xcd * 2 + (bl & 1);
    const int b = bl >> 1;
    const int qi = (qp & 1) ? (15 - (qp >> 1)) : (qp >> 1);   // work-pairing
    const int q0 = qi * 64;
    const int nt = qi + 17;
    const int jbase0 = (Q_ - 64) - q0;   // logical R row 0 -> global j

    // ---- Q frags: direct per-lane load + bias fuse (qbf [B*KL], x rows) ----
    size_t qrow = ((size_t)(b * KL_ + M_ + q0 + 16 * w + l15)) * 1024 + h * 64;
    union U8 { uint4 u; unsigned short us[8]; };
    U8 qa, qb2;
    qa.u  = *(const uint4*)(qbf + qrow + 8 * l4);
    qb2.u = *(const uint4*)(qbf + qrow + 32 + 8 * l4);
    short8v qwf0, qwf1, qrf0, qrf1;
#pragma unroll
    for (int i = 0; i < 8; i++) {
        float qv0 = bf2f(qa.us[i]), qv1 = bf2f(qb2.us[i]);
        int c0 = h * 64 + 8 * l4 + i, c1 = c0 + 32;
        qwf0[i] = f2bf(qv0 + rwb[c0]); qwf1[i] = f2bf(qv1 + rwb[c1]);
        qrf0[i] = f2bf(qv0 + rrb[c0]); qrf1[i] = f2bf(qv1 + rrb[c1]);
    }

    // ---- prologue: K(0),K(1) -> K_s, R logical [0,256) -> ring, V(0) -> V_T[0] ----
#pragma unroll
    for (int c = 0; c < 2; c++) {
        int R0 = 16 * w + 8 * c;
        int row = R0 + lr8;
        gload_lds16(kbf + ((size_t)(b * KL_) + row) * 1024 + h * 64 + ((oct * 8) ^ swz(row)),
                    &K_s[0][R0 * 64]);
        gload_lds16(kbf + ((size_t)(b * KL_) + 64 + row) * 1024 + h * 64 + ((oct * 8) ^ swz(row)),
                    &K_s[1][R0 * 64]);
    }
#pragma unroll
    for (int c = 0; c < 8; c++) {
        int R0 = 64 * w + 8 * c;
        int row = R0 + lr8;
        int jl = jbase0 + row;   // < KL
        gload_lds16(rbh + (size_t)jl * 1024 + h * 64 + ((oct * 8) ^ swz(row)),
                    &R_s[R0 * 64]);
    }
    {
        U8 cv0[2];
#pragma unroll
        for (int it = 0; it < 2; it++) {
            int rr = (tid + it * 256) >> 3;
            cv0[it].u = *(const uint4*)(vbf + ((size_t)(b * KL_) + rr) * 1024 + h * 64 + d0);
        }
#pragma unroll
        for (int it = 0; it < 2; it++) {
            int rr = (tid + it * 256) >> 3;
            int kp = kperm(rr);
#pragma unroll
            for (int i = 0; i < 8; i++)
                V_T[0][(d0 + i) * 64 + (kp ^ swz(d0 + i))] = (short)cv0[it].us[i];
        }
    }
    asm volatile("s_waitcnt vmcnt(0) lgkmcnt(0)" ::: "memory");
    __builtin_amdgcn_sched_barrier(0);
    __builtin_amdgcn_s_barrier();
    __builtin_amdgcn_sched_barrier(0);

    f32x4 o[4];
    float m_r[4], l_p[4];
#pragma unroll
    for (int j = 0; j < 4; j++) o[j] = (f32x4){0.f, 0.f, 0.f, 0.f};
#pragma unroll
    for (int r = 0; r < 4; r++) { m_r[r] = -1e30f; l_p[r] = 0.0f; }

    int sl[4];
#pragma unroll
    for (int r = 0; r < 4; r++)
        sl[r] = (lane & 48) | ((l15 + 15 - (4 * l4 + r)) & 15);

    short* P_w = &P_s[w][0];
    const int rbase = 16 * (3 - w);

    // ---- pre-compute ac/zf for tile 0 ----
    f32x4 acA[4], zfA[5], acB[4], zfB[5];
#pragma unroll
    for (int j = 0; j < 4; j++) {
        int kk = 16 * j + l15, sz = swz(kk);
        short8v b0 = *(const short8v*)&K_s[0][kk * 64 + ((8 * l4) ^ sz)];
        short8v b1 = *(const short8v*)&K_s[0][kk * 64 + ((32 + 8 * l4) ^ sz)];
        f32x4 z = {0.f, 0.f, 0.f, 0.f};
        z = __builtin_amdgcn_mfma_f32_16x16x32_bf16(qwf0, b0, z, 0, 0, 0);
        z = __builtin_amdgcn_mfma_f32_16x16x32_bf16(qwf1, b1, z, 0, 0, 0);
        acA[j] = z;
    }
#pragma unroll
    for (int jb = 0; jb < 5; jb++) {
        int rp = (rbase + 16 * jb + l15) & 255;
        int sz = swz(rp);
        short8v b0 = *(const short8v*)&R_s[rp * 64 + ((8 * l4) ^ sz)];
        short8v b1 = *(const short8v*)&R_s[rp * 64 + ((32 + 8 * l4) ^ sz)];
        f32x4 z = {0.f, 0.f, 0.f, 0.f};
        z = __builtin_amdgcn_mfma_f32_16x16x32_bf16(qrf0, b0, z, 0, 0, 0);
        z = __builtin_amdgcn_mfma_f32_16x16x32_bf16(qrf1, b1, z, 0, 0, 0);
        zfA[jb] = z;
    }

    auto body = [&](f32x4 (&ac)[4], f32x4 (&zf)[5], f32x4 (&acn)[4], f32x4 (&zfn)[5], int t)
        __attribute__((always_inline)) {
        const int cb = t & 1, nb = (t + 1) & 1;
        // ---- (a) issue next loads ----
        uint4 pv2[2];
        if (t + 1 < nt) {
#pragma unroll
            for (int it = 0; it < 2; it++) {
                int rr = (tid + it * 256) >> 3;
                pv2[it] = *(const uint4*)(vbf + ((size_t)(b * KL_) + 64 * (t + 1) + rr) * 1024 + h * 64 + d0);
            }
        }
        if (t + 2 < nt) {
#pragma unroll
            for (int c = 0; c < 2; c++) {
                int R0 = 16 * w + 8 * c;
                int row = R0 + lr8;
                gload_lds16(kbf + ((size_t)(b * KL_) + 64 * (t + 2) + row) * 1024 + h * 64 + ((oct * 8) ^ swz(row)),
                            &K_s[cb][R0 * 64]);
            }
            // R ring chunk: logical [64t+256, 64t+320)
#pragma unroll
            for (int c = 0; c < 2; c++) {
                int R0 = 16 * w + 8 * c;
                int l0 = 64 * t + 256 + R0 + lr8;
                int ph = l0 & 255;
                int jl = jbase0 + l0;
                if (jl > KL_ - 1) jl = KL_ - 1;
                gload_lds16(rbh + (size_t)jl * 1024 + h * 64 + ((oct * 8) ^ swz(ph)),
                            &R_s[((64 * t + 256 + R0) & 255) * 64]);
            }
        }
        __builtin_amdgcn_sched_barrier(0);   // keep load issues ahead

        // ---- (b) MFMA for tile t+1 (overlaps softmax(t) below) ----
        if (t + 1 < nt) {
            __builtin_amdgcn_s_setprio(1);
#pragma unroll
            for (int j = 0; j < 4; j++) {
                int kk = 16 * j + l15, sz = swz(kk);
                short8v b0 = *(const short8v*)&K_s[nb][kk * 64 + ((8 * l4) ^ sz)];
                short8v b1 = *(const short8v*)&K_s[nb][kk * 64 + ((32 + 8 * l4) ^ sz)];
                f32x4 z = {0.f, 0.f, 0.f, 0.f};
                z = __builtin_amdgcn_mfma_f32_16x16x32_bf16(qwf0, b0, z, 0, 0, 0);
                z = __builtin_amdgcn_mfma_f32_16x16x32_bf16(qwf1, b1, z, 0, 0, 0);
                acn[j] = z;
            }
#pragma unroll
            for (int jb = 0; jb < 5; jb++) {
                int rp = (64 * (t + 1) + rbase + 16 * jb + l15) & 255;
                int sz = swz(rp);
                short8v b0 = *(const short8v*)&R_s[rp * 64 + ((8 * l4) ^ sz)];
                short8v b1 = *(const short8v*)&R_s[rp * 64 + ((32 + 8 * l4) ^ sz)];
                f32x4 z = {0.f, 0.f, 0.f, 0.f};
                z = __builtin_amdgcn_mfma_f32_16x16x32_bf16(qrf0, b0, z, 0, 0, 0);
                z = __builtin_amdgcn_mfma_f32_16x16x32_bf16(qrf1, b1, z, 0, 0, 0);
                zfn[jb] = z;
            }
            __builtin_amdgcn_s_setprio(0);
        }

        // ---- (c) softmax(t): dedup BD shuffles, defer-max, lane-partial l ----
        float sv[4][4], lmax[4];
#pragma unroll
        for (int r = 0; r < 4; r++) {
            int row = 4 * l4 + r;
            float bq[5];
#pragma unroll
            for (int s = 0; s < 5; s++) bq[s] = __shfl(zf[s][r], sl[r]);
#pragma unroll
            for (int j = 0; j < 4; j++) {
                float bd = (l15 > row) ? bq[j + 1] : bq[j];
                sv[j][r] = (ac[j][r] + bd) * 0.125f;
            }
        }
        if (t == nt - 1) {   // only the final tile has masked elements
#pragma unroll
            for (int j = 0; j < 4; j++)
#pragma unroll
                for (int r = 0; r < 4; r++)
                    if (64 * t + 16 * j + l15 > q0 + 16 * w + 4 * l4 + r + M_) sv[j][r] = -1e30f;
        }
#pragma unroll
        for (int r = 0; r < 4; r++) lmax[r] = fmaxf(fmaxf(sv[0][r], sv[1][r]), fmaxf(sv[2][r], sv[3][r]));
        bool ok = true;
#pragma unroll
        for (int r = 0; r < 4; r++) ok = ok && (lmax[r] <= m_r[r] + 8.0f);
        if (!__all(ok)) {
#pragma unroll
            for (int r = 0; r < 4; r++) {
                float v = lmax[r];
                v = fmaxf(v, __shfl_xor(v, 1));
                v = fmaxf(v, __shfl_xor(v, 2));
                v = fmaxf(v, __shfl_xor(v, 4));
                v = fmaxf(v, __shfl_xor(v, 8));
                float mnew = fmaxf(m_r[r], v);
                float c = __expf(m_r[r] - mnew);
                m_r[r] = mnew;
                l_p[r] *= c;
#pragma unroll
                for (int jd = 0; jd < 4; jd++) o[jd][r] *= c;
            }
        }
#pragma unroll
        for (int j = 0; j < 4; j++)
#pragma unroll
            for (int r = 0; r < 4; r++) {
                float pp = __expf(sv[j][r] - m_r[r]);
                sv[j][r] = pp;
                l_p[r] += pp;
            }

        // ---- (d) P -> per-wave swizzled LDS (k-permuted, 1 b64/row) -> A-frags; PV ----
#pragma unroll
        for (int r = 0; r < 4; r++) {
            int row = 4 * l4 + r;
            uint2 pv;
            pv.x = cvtpk(sv[0][r], sv[1][r]);
            pv.y = cvtpk(sv[2][r], sv[3][r]);
            *(uint2*)&P_w[row * 64 + ((4 * l15) ^ swz(row))] = pv;
        }
        int szp = swz(l15);
        short8v pa0 = *(const short8v*)&P_w[l15 * 64 + ((8 * l4) ^ szp)];
        short8v pa1 = *(const short8v*)&P_w[l15 * 64 + ((32 + 8 * l4) ^ szp)];
        __builtin_amdgcn_s_setprio(1);
#pragma unroll
        for (int jd = 0; jd < 4; jd++) {
            int dd = 16 * jd + l15, sz = swz(dd);
            short8v v0 = *(const short8v*)&V_T[cb][dd * 64 + ((8 * l4) ^ sz)];
            short8v v1 = *(const short8v*)&V_T[cb][dd * 64 + ((32 + 8 * l4) ^ sz)];
            o[jd] = __builtin_amdgcn_mfma_f32_16x16x32_bf16(pa0, v0, o[jd], 0, 0, 0);
            o[jd] = __builtin_amdgcn_mfma_f32_16x16x32_bf16(pa1, v1, o[jd], 0, 0, 0);
        }
        __builtin_amdgcn_s_setprio(0);

        // ---- (e) write V(t+1) into V_T[nb] (k-permuted) ----
        if (t + 1 < nt) {
#pragma unroll
            for (int it = 0; it < 2; it++) {
                int rr = (tid + it * 256) >> 3;
                int kp = kperm(rr);
                U8 cv; cv.u = pv2[it];
#pragma unroll
                for (int i = 0; i < 8; i++)
                    V_T[nb][(d0 + i) * 64 + (kp ^ swz(d0 + i))] = (short)cv.us[i];
            }
            // ---- (f) single per-tile drain + barrier ----
            asm volatile("s_waitcnt vmcnt(0) lgkmcnt(0)" ::: "memory");
            __builtin_amdgcn_sched_barrier(0);
            __builtin_amdgcn_s_barrier();
            __builtin_amdgcn_sched_barrier(0);
        }
    };

    int t = 0;
    while (t < nt) {
        body(acA, zfA, acB, zfB, t); t++;
        if (t >= nt) break;
        body(acB, zfB, acA, zfA, t); t++;
    }

    // ---- final l reduce + normalize + store ----
    float l_r[4];
#pragma unroll
    for (int r = 0; r < 4; r++) {
        float v = l_p[r];
        v += __shfl_xor(v, 1);
        v += __shfl_xor(v, 2);
        v += __shfl_xor(v, 4);
        v += __shfl_xor(v, 8);
        l_r[r] = v;
    }
#pragma unroll
    for (int jd = 0; jd < 4; jd++) {
#pragma unroll
        for (int r = 0; r < 4; r++) {
            int qg = q0 + 16 * w + 4 * l4 + r;
            int dv = 16 * jd + l15;
            attnob[((size_t)(b * Q_ + qg)) * (H_ * DH_) + h * 64 + dv] = f2bf(o[jd][r] / l_r[r]);
        }
    }
}

// ---------------- layernorm: x = LN(x + a1 + a2) * g + b ; dual f32+bf16 out ----------------
__global__ __launch_bounds__(256) void ln_kernel(float* __restrict__ x,
                                                 short* __restrict__ xb,
                                                 const float* __restrict__ a1,
                                                 const float* __restrict__ a2,
                                                 const float* __restrict__ g,
                                                 const float* __restrict__ bb) {
    __shared__ float red[8];
    int row = blockIdx.x;
    int tid = threadIdx.x;
    float4 xv = ((const float4*)(x + (size_t)row * D_))[tid];
    float4 v1 = ((const float4*)(a1 + (size_t)row * D_))[tid];
    float4 v2 = ((const float4*)(a2 + (size_t)row * D_))[tid];
    float4 v;
    v.x = xv.x + v1.x + v2.x; v.y = xv.y + v1.y + v2.y;
    v.z = xv.z + v1.z + v2.z; v.w = xv.w + v1.w + v2.w;
    float s = v.x + v.y + v.z + v.w;
#pragma unroll
    for (int off = 32; off; off >>= 1) s += __shfl_xor(s, off);
    if ((tid & 63) == 0) red[tid >> 6] = s;
    __syncthreads();
    float mu = (red[0] + red[1] + red[2] + red[3]) * (1.0f / D_);
    float e0 = v.x - mu, e1 = v.y - mu, e2 = v.z - mu, e3 = v.w - mu;
    float sq = e0 * e0 + e1 * e1 + e2 * e2 + e3 * e3;
#pragma unroll
    for (int off = 32; off; off >>= 1) sq += __shfl_xor(sq, off);
    if ((tid & 63) == 0) red[4 + (tid >> 6)] = sq;
    __syncthreads();
    float var = (red[4] + red[5] + red[6] + red[7]) * (1.0f / D_);
    float rs = rsqrtf(var + 1e-5f);
    float4 gv = ((const float4*)g)[tid];
    float4 bv = ((const float4*)bb)[tid];
    float4 ov;
    ov.x = e0 * rs * gv.x + bv.x; ov.y = e1 * rs * gv.y + bv.y;
    ov.z = e2 * rs * gv.z + bv.z; ov.w = e3 * rs * gv.w + bv.w;
    ((float4*)(x + (size_t)row * D_))[tid] = ov;
    uint2 ob;
    ob.x = pack2bf(ov.x, ov.y);
    ob.y = pack2bf(ov.z, ov.w);
    *(uint2*)(xb + (size_t)row * D_ + tid * 4) = ob;
}

extern "C" void kernel_launch(void* const* d_in, const int* in_sizes, int n_in,
                              void* d_out, int out_size, void* d_ws, size_t ws_size,
                              hipStream_t stream) {
    const float* x    = (const float*)d_in[0];
    const float* mem  = (const float*)d_in[1];
    const float* Wqkv = (const float*)d_in[2];
    const float* Wr   = (const float*)d_in[3];
    const float* Wo   = (const float*)d_in[4];
    const float* rwb  = (const float*)d_in[5];
    const float* rrb  = (const float*)d_in[6];
    const float* ln1g = (const float*)d_in[7];
    const float* ln1b = (const float*)d_in[8];
    const float* ln2g = (const float*)d_in[9];
    const float* ln2b = (const float*)d_in[10];
    const float* Wff1 = (const float*)d_in[11];
    const float* bff1 = (const float*)d_in[12];
    const float* Wff2 = (const float*)d_in[13];
    const float* bff2 = (const float*)d_in[14];

    float* xc = (float*)d_out;

    // workspace layout (shorts unless noted)
    short* WqkvT = (short*)d_ws;              // [3072][1024]
    short* WoT   = WqkvT + 3145728;           // [1024][1024]
    short* Wff1T = WoT + 1048576;             // [4096][1024]
    short* Wff2T = Wff1T + 4194304;           // [1024][4096]
    short* WrT   = Wff2T + 4194304;           // [1024][1024]
    short* rbh   = WrT + 1048576;             // [2048][1024]
    short* xmemb = rbh + 2097152;             // [B*KL][1024]
    short* qbf   = xmemb + 4194304;           // [B*KL][1024] (x rows used)
    short* kbf   = qbf + 4194304;             // [B*KL][1024]
    short* vbf   = kbf + 4194304;             // [B*KL][1024]
    short* attnob= vbf + 4194304;             // [B*Q][1024]
    short* xcb   = attnob + 2097152;          // [B*Q][1024]
    short* ff1ob = xcb + 2097152;             // [B*Q][4096]
    float* addbuf= (float*)(ff1ob + 8388608); // [2][B*Q][1024] f32 (split-K partials)
    short* pbf   = ff1ob;                     // alias: p bf16 [2048][1024], pre-loop only

    // r = p @ W_r  (bf16 MFMA)
    transp_bf<<<dim3(32, 32), 256, 0, stream>>>(Wr, WrT, 1024, 1024);
    pos_emb_bf<<<(KL_ * D_) / 256, 256, 0, stream>>>(pbf);
    gemm_bf<0, 0, 1, 64><<<dim3(16, 16), 256, 0, stream>>>(
        pbf, WrT, nullptr, nullptr, rbh, nullptr, nullptr, KL_, 1024, 1024);

    hipMemcpyAsync(xc, x, (size_t)B_ * Q_ * D_ * sizeof(float),
                   hipMemcpyDeviceToDevice, stream);

    for (int l = 0; l < L_; l++) {
        const float* mem_l = mem + (size_t)l * B_ * M_ * D_;

        prep_layer<<<16384, 256, 0, stream>>>(
            Wqkv + (size_t)l * 3145728, Wo + (size_t)l * 1048576,
            Wff1 + (size_t)l * 4194304, Wff2 + (size_t)l * 4194304,
            WqkvT, WoT, Wff1T, Wff2T, mem_l, xc, xmemb);

        // fused QKV: flat 640-wg grid, skips Q-cols x mem-rows quadrant
        gemm_bf<0, 0, 2, 128, 1, 1><<<640, 256, 0, stream>>>(
            xmemb, WqkvT, nullptr, nullptr, qbf, kbf, vbf, B_ * KL_, 3072, 1024);

        attn_mfma<<<B_ * H_ * (Q_ / 64), 256, 0, stream>>>(
            qbf, kbf, vbf, rbh, rwb, rrb, attnob);

        gemm_bf<0, 0, 0, 64, 2><<<dim3(16, 16, 2), 256, 0, stream>>>(
            attnob, WoT, nullptr, addbuf, nullptr, nullptr, nullptr, B_ * Q_, 1024, 1024);

        ln_kernel<<<B_ * Q_, 256, 0, stream>>>(xc, xcb, addbuf, addbuf + 2097152,
                                               ln1g + l * D_, ln1b + l * D_);

        gemm_bf<1, 1, 1, 128><<<dim3(32, 16), 256, 0, stream>>>(
            xcb, Wff1T, bff1 + (size_t)l * DI_, nullptr, ff1ob, nullptr, nullptr, B_ * Q_, 4096, 1024);

        gemm_bf<1, 0, 0, 64, 2><<<dim3(16, 16, 2), 256, 0, stream>>>(
            ff1ob, Wff2T, bff2 + (size_t)l * D_, addbuf, nullptr, nullptr, nullptr, B_ * Q_, 1024, 4096);

        ln_kernel<<<B_ * Q_, 256, 0, stream>>>(xc, xcb, addbuf, addbuf + 2097152,
                                               ln2g + l * D_, ln2b + l * D_);
    }
}

// Round 15
// 914.020 us; speedup vs baseline: 1.1477x; 1.0226x over previous
//
#include <hip/hip_runtime.h>
#include <math.h>

#define L_  4
#define B_  2
#define Q_  1024
#define M_  1024
#define D_  1024
#define H_  16
#define DH_ 64
#define DI_ 4096
#define KL_ (M_ + Q_)   // 2048

typedef __attribute__((ext_vector_type(8))) short short8v;  // 8 bf16 (4 VGPRs)
typedef __attribute__((ext_vector_type(4))) float f32x4;

__device__ __forceinline__ short f2bf(float f) {
    union { float f; unsigned u; } x; x.f = f;
    return (short)((x.u + 0x7FFFu + ((x.u >> 16) & 1)) >> 16);  // RNE
}
__device__ __forceinline__ unsigned pack2bf(float a, float b) {
    return (unsigned)(unsigned short)f2bf(a) | ((unsigned)(unsigned short)f2bf(b) << 16);
}
__device__ __forceinline__ float bf2f(unsigned short u) {
    union { unsigned u; float f; } x; x.u = (unsigned)u << 16; return x.f;
}
__device__ __forceinline__ unsigned cvtpk(float lo, float hi) {
    unsigned r;
    asm("v_cvt_pk_bf16_f32 %0, %1, %2" : "=v"(r) : "v"(lo), "v"(hi));
    return r;
}
__device__ __forceinline__ void gload_lds16(const short* g, short* l) {
    __builtin_amdgcn_global_load_lds((const __attribute__((address_space(1))) unsigned int*)(const void*)g,
                                     (__attribute__((address_space(3))) unsigned int*)(void*)l, 16, 0, 0);
}
// XOR swizzle key (in shorts) for stride-64-short LDS tiles
__device__ __forceinline__ int swz(int row) {
    return ((row & 7) ^ ((row >> 3) & 7)) << 3;
}
// k-permutation for the PV contraction (applied to BOTH P and V_T k index)
__device__ __forceinline__ int kperm(int k) {
    return 4 * (k & 15) + (k >> 4);
}

// ---------------- positional embedding p[KL][D] (bf16) ----------------
__global__ __launch_bounds__(256) void pos_emb_bf(short* __restrict__ p) {
    int idx = blockIdx.x * 256 + threadIdx.x;
    int k = idx >> 10;
    int i = idx & (D_ - 1);
    float pos = (float)(KL_ - 1 - k);
    int j = (i < D_ / 2) ? i : (i - D_ / 2);
    float invf = powf(10000.0f, -((float)(2 * j) / (float)D_));
    float ang = pos * invf;
    p[idx] = f2bf((i < D_ / 2) ? sinf(ang) : cosf(ang));
}

// ---------------- tiled transpose + f32->bf16: in[K][N] -> out[N][K] ----------------
__global__ __launch_bounds__(256) void transp_bf(const float* __restrict__ in,
                                                 short* __restrict__ out,
                                                 int K, int N) {
    __shared__ float t[32][33];
    int r = threadIdx.x >> 3, c4 = (threadIdx.x & 7) * 4;
    float4 v = *(const float4*)(in + (size_t)(blockIdx.y * 32 + r) * N + blockIdx.x * 32 + c4);
    t[r][c4 + 0] = v.x; t[r][c4 + 1] = v.y; t[r][c4 + 2] = v.z; t[r][c4 + 3] = v.w;
    __syncthreads();
    uint2 o;
    o.x = pack2bf(t[c4 + 0][r], t[c4 + 1][r]);
    o.y = pack2bf(t[c4 + 2][r], t[c4 + 3][r]);
    *(uint2*)(out + (size_t)(blockIdx.x * 32 + r) * K + blockIdx.y * 32 + c4) = o;
}

// ---------------- per-layer prep: 4 weight transposes + concat, one flat grid ----------------
__global__ __launch_bounds__(256) void prep_layer(const float* __restrict__ Wqkv_l,
                                                  const float* __restrict__ Wo_l,
                                                  const float* __restrict__ Wff1_l,
                                                  const float* __restrict__ Wff2_l,
                                                  short* __restrict__ WqkvT,
                                                  short* __restrict__ WoT,
                                                  short* __restrict__ Wff1T,
                                                  short* __restrict__ Wff2T,
                                                  const float* __restrict__ mem_l,
                                                  const float* __restrict__ xc,
                                                  short* __restrict__ xmemb) {
    const int id = blockIdx.x;
    const int tid = threadIdx.x;
    if (id >= 12288) {                       // concat: 4 bf16 elems/thread
        int idx = ((id - 12288) * 256 + tid) * 4;
        int d = idx & (D_ - 1);
        int k = (idx >> 10) & (KL_ - 1);
        int b = idx >> 21;
        const float* src = (k < M_) ? (mem_l + ((size_t)(b * M_ + k)) * D_ + d)
                                    : (xc + ((size_t)(b * Q_ + (k - M_))) * D_ + d);
        float4 v = *(const float4*)src;
        uint2 o; o.x = pack2bf(v.x, v.y); o.y = pack2bf(v.z, v.w);
        *(uint2*)(xmemb + idx) = o;
        return;
    }
    // transpose tile
    const float* in; short* out; int K, N, bx, by;
    if (id < 3072)      { in = Wqkv_l; out = WqkvT; K = 1024; N = 3072; bx = id % 96;  by = id / 96; }
    else if (id < 4096) { int t2 = id - 3072; in = Wo_l;   out = WoT;   K = 1024; N = 1024; bx = t2 & 31;  by = t2 >> 5; }
    else if (id < 8192) { int t2 = id - 4096; in = Wff1_l; out = Wff1T; K = 1024; N = 4096; bx = t2 & 127; by = t2 >> 7; }
    else                { int t2 = id - 8192; in = Wff2_l; out = Wff2T; K = 4096; N = 1024; bx = t2 & 31;  by = t2 >> 5; }
    __shared__ float t[32][33];
    int r = tid >> 3, c4 = (tid & 7) * 4;
    float4 v = *(const float4*)(in + (size_t)(by * 32 + r) * N + bx * 32 + c4);
    t[r][c4 + 0] = v.x; t[r][c4 + 1] = v.y; t[r][c4 + 2] = v.z; t[r][c4 + 3] = v.w;
    __syncthreads();
    uint2 o;
    o.x = pack2bf(t[c4 + 0][r], t[c4 + 1][r]);
    o.y = pack2bf(t[c4 + 2][r], t[c4 + 3][r]);
    *(uint2*)(out + (size_t)(bx * 32 + r) * K + by * 32 + c4) = o;
}

// ---------------- bf16 MFMA GEMM: C[M,N] = A[M,K] @ BT[N,K]^T ----------------
template <int BIAS, int RELU, int OMODE, int TN, int KS = 1, int QKVG = 0>
__global__ __launch_bounds__(256, 2) void gemm_bf(const short* __restrict__ A,
                                                  const short* __restrict__ BT,
                                                  const float* __restrict__ bias,
                                                  float* __restrict__ Cf,
                                                  short* __restrict__ C0,
                                                  short* __restrict__ C1,
                                                  short* __restrict__ C2,
                                                  int M, int N, int K) {
    __shared__ short A_s[128 * 32];
    __shared__ short B_s[TN * 32];
    const int tid = threadIdx.x;
    const int lane = tid & 63, w = tid >> 6;
    const int l15 = lane & 15, l4 = lane >> 4;
    constexpr int MF = (TN == 128) ? 4 : 2;
    const int wr = (TN == 128) ? (w >> 1) : w;
    const int wc = (TN == 128) ? (w & 1) : 0;
    const int arow0 = 32 * ((TN == 128) ? 2 * wr : w);
    const int brow0 = (TN == 128) ? 64 * wc : 0;
    int row0, col0;
    if constexpr (QKVG) {
        int id = blockIdx.x;
        if (id < 512) {                     // KV: 16 col-tiles x 32 row-tiles
            col0 = 1024 + (id & 15) * 128;
            row0 = (id >> 4) * 128;
        } else {                            // Q: 8 col-tiles x 16 x-row tiles
            int t2 = id - 512;
            col0 = (t2 & 7) * 128;
            int rt = t2 >> 3;               // 0..15
            rt = (rt < 8) ? (rt + 8) : (rt + 16);   // x rows: tiles 8..15, 24..31
            row0 = rt * 128;
        }
    } else {
        row0 = blockIdx.y * 128;
        col0 = blockIdx.x * TN;
    }
    const int kz = (KS == 2) ? blockIdx.z : 0;
    const int Kh = (KS == 2) ? (K >> 1) : K;
    const int kb = kz * Kh;

    const int lrow = lane >> 2;
    const int lk = (lane & 3) * 8;
    const short* Ag = A + (size_t)(row0 + 32 * w) * K;
    const short* Bg = BT + (size_t)(col0 + ((TN == 128) ? 32 : 16) * w) * K;

    f32x4 acc[MF][4] = {};

    for (int k0 = kb; k0 < kb + Kh; k0 += 32) {
        __syncthreads();
        gload_lds16(Ag + (size_t)lrow * K + k0 + lk,        &A_s[(32 * w) * 32]);
        gload_lds16(Ag + (size_t)(16 + lrow) * K + k0 + lk, &A_s[(32 * w + 16) * 32]);
        if (TN == 128) {
            gload_lds16(Bg + (size_t)lrow * K + k0 + lk,        &B_s[(32 * w) * 32]);
            gload_lds16(Bg + (size_t)(16 + lrow) * K + k0 + lk, &B_s[(32 * w + 16) * 32]);
        } else {
            gload_lds16(Bg + (size_t)lrow * K + k0 + lk,        &B_s[(16 * w) * 32]);
        }
        __syncthreads();
        short8v a[MF], bfr[4];
#pragma unroll
        for (int m = 0; m < MF; m++) a[m] = *(const short8v*)&A_s[(arow0 + 16 * m + l15) * 32 + 8 * l4];
#pragma unroll
        for (int n = 0; n < 4; n++) bfr[n] = *(const short8v*)&B_s[(brow0 + 16 * n + l15) * 32 + 8 * l4];
#pragma unroll
        for (int m = 0; m < MF; m++)
#pragma unroll
            for (int n = 0; n < 4; n++)
                acc[m][n] = __builtin_amdgcn_mfma_f32_16x16x32_bf16(a[m], bfr[n], acc[m][n], 0, 0, 0);
    }

    float* Cfz = Cf + (size_t)kz * M * N;
#pragma unroll
    for (int n = 0; n < 4; n++) {
        int col = col0 + brow0 + 16 * n + l15;
        float bv = (BIAS && (KS == 1 || kz == 0)) ? bias[col] : 0.0f;
#pragma unroll
        for (int m = 0; m < MF; m++) {
#pragma unroll
            for (int r = 0; r < 4; r++) {
                int row = row0 + arow0 + 16 * m + 4 * l4 + r;
                float v = acc[m][n][r] + bv;
                if (RELU) v = fmaxf(v, 0.0f);
                if (OMODE == 0) {
                    Cfz[(size_t)row * N + col] = v;
                } else if (OMODE == 1) {
                    C0[(size_t)row * N + col] = f2bf(v);
                } else {
                    int part = col >> 10, cc = col & 1023;
                    short* dst = part == 0 ? C0 : (part == 1 ? C1 : C2);
                    dst[(size_t)row * 1024 + cc] = f2bf(v);
                }
            }
        }
    }
}

// ---------------- MFMA fused attention v6 + kperm (load-balanced qi decode) ----------------
// 512 blocks. XCD pin: xcd=wg&7 serves h={2xcd,2xcd+1} x b. qi flipped for bl>=2 so
// co-resident pairs (k,k+32 OR k,k+1 within an XCD) have complementary nt -> every CU
// carries ~49 tiles total (removes the 32-vs-24.5 slowest-CU dispatch tail).
__global__ __launch_bounds__(256, 2) void attn_mfma(const short* __restrict__ qbf,
                                                    const short* __restrict__ kbf,
                                                    const short* __restrict__ vbf,
                                                    const short* __restrict__ rbh,
                                                    const float* __restrict__ rwb,
                                                    const float* __restrict__ rrb,
                                                    short* __restrict__ attnob) {
    __shared__ short K_s[2][64 * 64];
    __shared__ short V_T[2][64 * 64];   // V_T[d][kperm(k)], swizzled
    __shared__ short R_s[256 * 64];     // ring: phys = logical & 255
    __shared__ short P_s[4][16 * 64];   // per-wave P, k-permuted, swizzled

    const int tid = threadIdx.x;
    const int lane = tid & 63, w = tid >> 6;
    const int l15 = lane & 15, l4 = lane >> 4;
    const int lr8 = lane >> 3, oct = lane & 7;
    const int d0 = (tid & 7) * 8;

    // ---- XCD-pinned decode (512 blocks: xcd(8) x qp(16) x bl(4)) ----
    const int wg = blockIdx.x;
    const int xcd = wg & 7;
    const int qp = (wg >> 3) & 15;
    const int bl = (wg >> 7) & 3;
    const int h = xcd * 2 + (bl & 1);
    const int b = bl >> 1;
    int qi = (qp & 1) ? (15 - (qp >> 1)) : (qp >> 1);   // adjacent-k complementary
    if (bl >= 2) qi = 15 - qi;                          // (k,k+32) complementary
    const int q0 = qi * 64;
    const int nt = qi + 17;
    const int jbase0 = (Q_ - 64) - q0;   // logical R row 0 -> global j

    // ---- Q frags: direct per-lane load + bias fuse (qbf [B*KL], x rows) ----
    size_t qrow = ((size_t)(b * KL_ + M_ + q0 + 16 * w + l15)) * 1024 + h * 64;
    union U8 { uint4 u; unsigned short us[8]; };
    U8 qa, qb2;
    qa.u  = *(const uint4*)(qbf + qrow + 8 * l4);
    qb2.u = *(const uint4*)(qbf + qrow + 32 + 8 * l4);
    short8v qwf0, qwf1, qrf0, qrf1;
#pragma unroll
    for (int i = 0; i < 8; i++) {
        float qv0 = bf2f(qa.us[i]), qv1 = bf2f(qb2.us[i]);
        int c0 = h * 64 + 8 * l4 + i, c1 = c0 + 32;
        qwf0[i] = f2bf(qv0 + rwb[c0]); qwf1[i] = f2bf(qv1 + rwb[c1]);
        qrf0[i] = f2bf(qv0 + rrb[c0]); qrf1[i] = f2bf(qv1 + rrb[c1]);
    }

    // ---- prologue: K(0),K(1) -> K_s, R logical [0,256) -> ring, V(0) -> V_T[0] ----
#pragma unroll
    for (int c = 0; c < 2; c++) {
        int R0 = 16 * w + 8 * c;
        int row = R0 + lr8;
        gload_lds16(kbf + ((size_t)(b * KL_) + row) * 1024 + h * 64 + ((oct * 8) ^ swz(row)),
                    &K_s[0][R0 * 64]);
        gload_lds16(kbf + ((size_t)(b * KL_) + 64 + row) * 1024 + h * 64 + ((oct * 8) ^ swz(row)),
                    &K_s[1][R0 * 64]);
    }
#pragma unroll
    for (int c = 0; c < 8; c++) {
        int R0 = 64 * w + 8 * c;
        int row = R0 + lr8;
        int jl = jbase0 + row;   // < KL
        gload_lds16(rbh + (size_t)jl * 1024 + h * 64 + ((oct * 8) ^ swz(row)),
                    &R_s[R0 * 64]);
    }
    {
        U8 cv0[2];
#pragma unroll
        for (int it = 0; it < 2; it++) {
            int rr = (tid + it * 256) >> 3;
            cv0[it].u = *(const uint4*)(vbf + ((size_t)(b * KL_) + rr) * 1024 + h * 64 + d0);
        }
#pragma unroll
        for (int it = 0; it < 2; it++) {
            int rr = (tid + it * 256) >> 3;
            int kp = kperm(rr);
#pragma unroll
            for (int i = 0; i < 8; i++)
                V_T[0][(d0 + i) * 64 + (kp ^ swz(d0 + i))] = (short)cv0[it].us[i];
        }
    }
    asm volatile("s_waitcnt vmcnt(0) lgkmcnt(0)" ::: "memory");
    __builtin_amdgcn_sched_barrier(0);
    __builtin_amdgcn_s_barrier();
    __builtin_amdgcn_sched_barrier(0);

    f32x4 o[4];
    float m_r[4], l_p[4];
#pragma unroll
    for (int j = 0; j < 4; j++) o[j] = (f32x4){0.f, 0.f, 0.f, 0.f};
#pragma unroll
    for (int r = 0; r < 4; r++) { m_r[r] = -1e30f; l_p[r] = 0.0f; }

    int sl[4];
#pragma unroll
    for (int r = 0; r < 4; r++)
        sl[r] = (lane & 48) | ((l15 + 15 - (4 * l4 + r)) & 15);

    short* P_w = &P_s[w][0];
    const int rbase = 16 * (3 - w);

    // ---- pre-compute ac/zf for tile 0 ----
    f32x4 acA[4], zfA[5], acB[4], zfB[5];
#pragma unroll
    for (int j = 0; j < 4; j++) {
        int kk = 16 * j + l15, sz = swz(kk);
        short8v b0 = *(const short8v*)&K_s[0][kk * 64 + ((8 * l4) ^ sz)];
        short8v b1 = *(const short8v*)&K_s[0][kk * 64 + ((32 + 8 * l4) ^ sz)];
        f32x4 z = {0.f, 0.f, 0.f, 0.f};
        z = __builtin_amdgcn_mfma_f32_16x16x32_bf16(qwf0, b0, z, 0, 0, 0);
        z = __builtin_amdgcn_mfma_f32_16x16x32_bf16(qwf1, b1, z, 0, 0, 0);
        acA[j] = z;
    }
#pragma unroll
    for (int jb = 0; jb < 5; jb++) {
        int rp = (rbase + 16 * jb + l15) & 255;
        int sz = swz(rp);
        short8v b0 = *(const short8v*)&R_s[rp * 64 + ((8 * l4) ^ sz)];
        short8v b1 = *(const short8v*)&R_s[rp * 64 + ((32 + 8 * l4) ^ sz)];
        f32x4 z = {0.f, 0.f, 0.f, 0.f};
        z = __builtin_amdgcn_mfma_f32_16x16x32_bf16(qrf0, b0, z, 0, 0, 0);
        z = __builtin_amdgcn_mfma_f32_16x16x32_bf16(qrf1, b1, z, 0, 0, 0);
        zfA[jb] = z;
    }

    auto body = [&](f32x4 (&ac)[4], f32x4 (&zf)[5], f32x4 (&acn)[4], f32x4 (&zfn)[5], int t)
        __attribute__((always_inline)) {
        const int cb = t & 1, nb = (t + 1) & 1;
        // ---- (a) issue next loads ----
        uint4 pv2[2];
        if (t + 1 < nt) {
#pragma unroll
            for (int it = 0; it < 2; it++) {
                int rr = (tid + it * 256) >> 3;
                pv2[it] = *(const uint4*)(vbf + ((size_t)(b * KL_) + 64 * (t + 1) + rr) * 1024 + h * 64 + d0);
            }
        }
        if (t + 2 < nt) {
#pragma unroll
            for (int c = 0; c < 2; c++) {
                int R0 = 16 * w + 8 * c;
                int row = R0 + lr8;
                gload_lds16(kbf + ((size_t)(b * KL_) + 64 * (t + 2) + row) * 1024 + h * 64 + ((oct * 8) ^ swz(row)),
                            &K_s[cb][R0 * 64]);
            }
            // R ring chunk: logical [64t+256, 64t+320)
#pragma unroll
            for (int c = 0; c < 2; c++) {
                int R0 = 16 * w + 8 * c;
                int l0 = 64 * t + 256 + R0 + lr8;
                int ph = l0 & 255;
                int jl = jbase0 + l0;
                if (jl > KL_ - 1) jl = KL_ - 1;
                gload_lds16(rbh + (size_t)jl * 1024 + h * 64 + ((oct * 8) ^ swz(ph)),
                            &R_s[((64 * t + 256 + R0) & 255) * 64]);
            }
        }
        __builtin_amdgcn_sched_barrier(0);   // keep load issues ahead

        // ---- (b) MFMA for tile t+1 (overlaps softmax(t) below) ----
        if (t + 1 < nt) {
            __builtin_amdgcn_s_setprio(1);
#pragma unroll
            for (int j = 0; j < 4; j++) {
                int kk = 16 * j + l15, sz = swz(kk);
                short8v b0 = *(const short8v*)&K_s[nb][kk * 64 + ((8 * l4) ^ sz)];
                short8v b1 = *(const short8v*)&K_s[nb][kk * 64 + ((32 + 8 * l4) ^ sz)];
                f32x4 z = {0.f, 0.f, 0.f, 0.f};
                z = __builtin_amdgcn_mfma_f32_16x16x32_bf16(qwf0, b0, z, 0, 0, 0);
                z = __builtin_amdgcn_mfma_f32_16x16x32_bf16(qwf1, b1, z, 0, 0, 0);
                acn[j] = z;
            }
#pragma unroll
            for (int jb = 0; jb < 5; jb++) {
                int rp = (64 * (t + 1) + rbase + 16 * jb + l15) & 255;
                int sz = swz(rp);
                short8v b0 = *(const short8v*)&R_s[rp * 64 + ((8 * l4) ^ sz)];
                short8v b1 = *(const short8v*)&R_s[rp * 64 + ((32 + 8 * l4) ^ sz)];
                f32x4 z = {0.f, 0.f, 0.f, 0.f};
                z = __builtin_amdgcn_mfma_f32_16x16x32_bf16(qrf0, b0, z, 0, 0, 0);
                z = __builtin_amdgcn_mfma_f32_16x16x32_bf16(qrf1, b1, z, 0, 0, 0);
                zfn[jb] = z;
            }
            __builtin_amdgcn_s_setprio(0);
        }

        // ---- (c) softmax(t): dedup BD shuffles, defer-max, lane-partial l ----
        float sv[4][4], lmax[4];
#pragma unroll
        for (int r = 0; r < 4; r++) {
            int row = 4 * l4 + r;
            float bq[5];
#pragma unroll
            for (int s = 0; s < 5; s++) bq[s] = __shfl(zf[s][r], sl[r]);
#pragma unroll
            for (int j = 0; j < 4; j++) {
                float bd = (l15 > row) ? bq[j + 1] : bq[j];
                sv[j][r] = (ac[j][r] + bd) * 0.125f;
            }
        }
        if (t == nt - 1) {   // only the final tile has masked elements
#pragma unroll
            for (int j = 0; j < 4; j++)
#pragma unroll
                for (int r = 0; r < 4; r++)
                    if (64 * t + 16 * j + l15 > q0 + 16 * w + 4 * l4 + r + M_) sv[j][r] = -1e30f;
        }
#pragma unroll
        for (int r = 0; r < 4; r++) lmax[r] = fmaxf(fmaxf(sv[0][r], sv[1][r]), fmaxf(sv[2][r], sv[3][r]));
        bool ok = true;
#pragma unroll
        for (int r = 0; r < 4; r++) ok = ok && (lmax[r] <= m_r[r] + 8.0f);
        if (!__all(ok)) {
#pragma unroll
            for (int r = 0; r < 4; r++) {
                float v = lmax[r];
                v = fmaxf(v, __shfl_xor(v, 1));
                v = fmaxf(v, __shfl_xor(v, 2));
                v = fmaxf(v, __shfl_xor(v, 4));
                v = fmaxf(v, __shfl_xor(v, 8));
                float mnew = fmaxf(m_r[r], v);
                float c = __expf(m_r[r] - mnew);
                m_r[r] = mnew;
                l_p[r] *= c;
#pragma unroll
                for (int jd = 0; jd < 4; jd++) o[jd][r] *= c;
            }
        }
#pragma unroll
        for (int j = 0; j < 4; j++)
#pragma unroll
            for (int r = 0; r < 4; r++) {
                float pp = __expf(sv[j][r] - m_r[r]);
                sv[j][r] = pp;
                l_p[r] += pp;
            }

        // ---- (d) P -> per-wave swizzled LDS (k-permuted, 1 b64/row) -> A-frags; PV ----
#pragma unroll
        for (int r = 0; r < 4; r++) {
            int row = 4 * l4 + r;
            uint2 pv;
            pv.x = cvtpk(sv[0][r], sv[1][r]);
            pv.y = cvtpk(sv[2][r], sv[3][r]);
            *(uint2*)&P_w[row * 64 + ((4 * l15) ^ swz(row))] = pv;
        }
        int szp = swz(l15);
        short8v pa0 = *(const short8v*)&P_w[l15 * 64 + ((8 * l4) ^ szp)];
        short8v pa1 = *(const short8v*)&P_w[l15 * 64 + ((32 + 8 * l4) ^ szp)];
        __builtin_amdgcn_s_setprio(1);
#pragma unroll
        for (int jd = 0; jd < 4; jd++) {
            int dd = 16 * jd + l15, sz = swz(dd);
            short8v v0 = *(const short8v*)&V_T[cb][dd * 64 + ((8 * l4) ^ sz)];
            short8v v1 = *(const short8v*)&V_T[cb][dd * 64 + ((32 + 8 * l4) ^ sz)];
            o[jd] = __builtin_amdgcn_mfma_f32_16x16x32_bf16(pa0, v0, o[jd], 0, 0, 0);
            o[jd] = __builtin_amdgcn_mfma_f32_16x16x32_bf16(pa1, v1, o[jd], 0, 0, 0);
        }
        __builtin_amdgcn_s_setprio(0);

        // ---- (e) write V(t+1) into V_T[nb] (k-permuted) ----
        if (t + 1 < nt) {
#pragma unroll
            for (int it = 0; it < 2; it++) {
                int rr = (tid + it * 256) >> 3;
                int kp = kperm(rr);
                U8 cv; cv.u = pv2[it];
#pragma unroll
                for (int i = 0; i < 8; i++)
                    V_T[nb][(d0 + i) * 64 + (kp ^ swz(d0 + i))] = (short)cv.us[i];
            }
            // ---- (f) single per-tile drain + barrier ----
            asm volatile("s_waitcnt vmcnt(0) lgkmcnt(0)" ::: "memory");
            __builtin_amdgcn_sched_barrier(0);
            __builtin_amdgcn_s_barrier();
            __builtin_amdgcn_sched_barrier(0);
        }
    };

    int t = 0;
    while (t < nt) {
        body(acA, zfA, acB, zfB, t); t++;
        if (t >= nt) break;
        body(acB, zfB, acA, zfA, t); t++;
    }

    // ---- final l reduce + normalize + store ----
    float l_r[4];
#pragma unroll
    for (int r = 0; r < 4; r++) {
        float v = l_p[r];
        v += __shfl_xor(v, 1);
        v += __shfl_xor(v, 2);
        v += __shfl_xor(v, 4);
        v += __shfl_xor(v, 8);
        l_r[r] = v;
    }
#pragma unroll
    for (int jd = 0; jd < 4; jd++) {
#pragma unroll
        for (int r = 0; r < 4; r++) {
            int qg = q0 + 16 * w + 4 * l4 + r;
            int dv = 16 * jd + l15;
            attnob[((size_t)(b * Q_ + qg)) * (H_ * DH_) + h * 64 + dv] = f2bf(o[jd][r] / l_r[r]);
        }
    }
}

// ---------------- layernorm: x = LN(x + a1 + a2) * g + b ; dual f32+bf16 out ----------------
__global__ __launch_bounds__(256) void ln_kernel(float* __restrict__ x,
                                                 short* __restrict__ xb,
                                                 const float* __restrict__ a1,
                                                 const float* __restrict__ a2,
                                                 const float* __restrict__ g,
                                                 const float* __restrict__ bb) {
    __shared__ float red[8];
    int row = blockIdx.x;
    int tid = threadIdx.x;
    float4 xv = ((const float4*)(x + (size_t)row * D_))[tid];
    float4 v1 = ((const float4*)(a1 + (size_t)row * D_))[tid];
    float4 v2 = ((const float4*)(a2 + (size_t)row * D_))[tid];
    float4 v;
    v.x = xv.x + v1.x + v2.x; v.y = xv.y + v1.y + v2.y;
    v.z = xv.z + v1.z + v2.z; v.w = xv.w + v1.w + v2.w;
    float s = v.x + v.y + v.z + v.w;
#pragma unroll
    for (int off = 32; off; off >>= 1) s += __shfl_xor(s, off);
    if ((tid & 63) == 0) red[tid >> 6] = s;
    __syncthreads();
    float mu = (red[0] + red[1] + red[2] + red[3]) * (1.0f / D_);
    float e0 = v.x - mu, e1 = v.y - mu, e2 = v.z - mu, e3 = v.w - mu;
    float sq = e0 * e0 + e1 * e1 + e2 * e2 + e3 * e3;
#pragma unroll
    for (int off = 32; off; off >>= 1) sq += __shfl_xor(sq, off);
    if ((tid & 63) == 0) red[4 + (tid >> 6)] = sq;
    __syncthreads();
    float var = (red[4] + red[5] + red[6] + red[7]) * (1.0f / D_);
    float rs = rsqrtf(var + 1e-5f);
    float4 gv = ((const float4*)g)[tid];
    float4 bv = ((const float4*)bb)[tid];
    float4 ov;
    ov.x = e0 * rs * gv.x + bv.x; ov.y = e1 * rs * gv.y + bv.y;
    ov.z = e2 * rs * gv.z + bv.z; ov.w = e3 * rs * gv.w + bv.w;
    ((float4*)(x + (size_t)row * D_))[tid] = ov;
    uint2 ob;
    ob.x = pack2bf(ov.x, ov.y);
    ob.y = pack2bf(ov.z, ov.w);
    *(uint2*)(xb + (size_t)row * D_ + tid * 4) = ob;
}

extern "C" void kernel_launch(void* const* d_in, const int* in_sizes, int n_in,
                              void* d_out, int out_size, void* d_ws, size_t ws_size,
                              hipStream_t stream) {
    const float* x    = (const float*)d_in[0];
    const float* mem  = (const float*)d_in[1];
    const float* Wqkv = (const float*)d_in[2];
    const float* Wr   = (const float*)d_in[3];
    const float* Wo   = (const float*)d_in[4];
    const float* rwb  = (const float*)d_in[5];
    const float* rrb  = (const float*)d_in[6];
    const float* ln1g = (const float*)d_in[7];
    const float* ln1b = (const float*)d_in[8];
    const float* ln2g = (const float*)d_in[9];
    const float* ln2b = (const float*)d_in[10];
    const float* Wff1 = (const float*)d_in[11];
    const float* bff1 = (const float*)d_in[12];
    const float* Wff2 = (const float*)d_in[13];
    const float* bff2 = (const float*)d_in[14];

    float* xc = (float*)d_out;

    // workspace layout (shorts unless noted)
    short* WqkvT = (short*)d_ws;              // [3072][1024]
    short* WoT   = WqkvT + 3145728;           // [1024][1024]
    short* Wff1T = WoT + 1048576;             // [4096][1024]
    short* Wff2T = Wff1T + 4194304;           // [1024][4096]
    short* WrT   = Wff2T + 4194304;           // [1024][1024]
    short* rbh   = WrT + 1048576;             // [2048][1024]
    short* xmemb = rbh + 2097152;             // [B*KL][1024]
    short* qbf   = xmemb + 4194304;           // [B*KL][1024] (x rows used)
    short* kbf   = qbf + 4194304;             // [B*KL][1024]
    short* vbf   = kbf + 4194304;             // [B*KL][1024]
    short* attnob= vbf + 4194304;             // [B*Q][1024]
    short* xcb   = attnob + 2097152;          // [B*Q][1024]
    short* ff1ob = xcb + 2097152;             // [B*Q][4096]
    float* addbuf= (float*)(ff1ob + 8388608); // [2][B*Q][1024] f32 (split-K partials)
    short* pbf   = ff1ob;                     // alias: p bf16 [2048][1024], pre-loop only

    // r = p @ W_r  (bf16 MFMA)
    transp_bf<<<dim3(32, 32), 256, 0, stream>>>(Wr, WrT, 1024, 1024);
    pos_emb_bf<<<(KL_ * D_) / 256, 256, 0, stream>>>(pbf);
    gemm_bf<0, 0, 1, 64><<<dim3(16, 16), 256, 0, stream>>>(
        pbf, WrT, nullptr, nullptr, rbh, nullptr, nullptr, KL_, 1024, 1024);

    hipMemcpyAsync(xc, x, (size_t)B_ * Q_ * D_ * sizeof(float),
                   hipMemcpyDeviceToDevice, stream);

    for (int l = 0; l < L_; l++) {
        const float* mem_l = mem + (size_t)l * B_ * M_ * D_;

        prep_layer<<<16384, 256, 0, stream>>>(
            Wqkv + (size_t)l * 3145728, Wo + (size_t)l * 1048576,
            Wff1 + (size_t)l * 4194304, Wff2 + (size_t)l * 4194304,
            WqkvT, WoT, Wff1T, Wff2T, mem_l, xc, xmemb);

        // fused QKV: flat 640-wg grid, skips Q-cols x mem-rows quadrant
        gemm_bf<0, 0, 2, 128, 1, 1><<<640, 256, 0, stream>>>(
            xmemb, WqkvT, nullptr, nullptr, qbf, kbf, vbf, B_ * KL_, 3072, 1024);

        attn_mfma<<<B_ * H_ * (Q_ / 64), 256, 0, stream>>>(
            qbf, kbf, vbf, rbh, rwb, rrb, attnob);

        gemm_bf<0, 0, 0, 64, 2><<<dim3(16, 16, 2), 256, 0, stream>>>(
            attnob, WoT, nullptr, addbuf, nullptr, nullptr, nullptr, B_ * Q_, 1024, 1024);

        ln_kernel<<<B_ * Q_, 256, 0, stream>>>(xc, xcb, addbuf, addbuf + 2097152,
                                               ln1g + l * D_, ln1b + l * D_);

        gemm_bf<1, 1, 1, 128><<<dim3(32, 16), 256, 0, stream>>>(
            xcb, Wff1T, bff1 + (size_t)l * DI_, nullptr, ff1ob, nullptr, nullptr, B_ * Q_, 4096, 1024);

        gemm_bf<1, 0, 0, 64, 2><<<dim3(16, 16, 2), 256, 0, stream>>>(
            ff1ob, Wff2T, bff2 + (size_t)l * D_, addbuf, nullptr, nullptr, nullptr, B_ * Q_, 1024, 4096);

        ln_kernel<<<B_ * Q_, 256, 0, stream>>>(xc, xcb, addbuf, addbuf + 2097152,
                                               ln2g + l * D_, ln2b + l * D_);
    }
}